// Round 7
// baseline (262.619 us; speedup 1.0000x reference)
//
#include <hip/hip_runtime.h>

typedef unsigned short u16;
typedef unsigned int   u32;

typedef __attribute__((ext_vector_type(8)))  short bf16x8;
typedef __attribute__((ext_vector_type(16))) float f32x16;
typedef __attribute__((ext_vector_type(2)))  unsigned int u32x2;
#define MFMA32(a, b, c) __builtin_amdgcn_mfma_f32_32x32x16_bf16(a, b, c, 0, 0, 0)

// ---------- bf16 helpers ----------
__device__ __forceinline__ float bf2f(u16 h) { return __uint_as_float(((u32)h) << 16); }
__device__ __forceinline__ u16 f2bf(float f) {
  u32 u = __float_as_uint(f);
  u += 0x7fffu + ((u >> 16) & 1u);   // RNE
  return (u16)(u >> 16);
}
__device__ __forceinline__ void unpack8(uint4 u, float* f) {
  f[0] = __uint_as_float(u.x << 16); f[1] = __uint_as_float(u.x & 0xffff0000u);
  f[2] = __uint_as_float(u.y << 16); f[3] = __uint_as_float(u.y & 0xffff0000u);
  f[4] = __uint_as_float(u.z << 16); f[5] = __uint_as_float(u.z & 0xffff0000u);
  f[6] = __uint_as_float(u.w << 16); f[7] = __uint_as_float(u.w & 0xffff0000u);
}
__device__ __forceinline__ void unpack4(uint2 u, float* f) {
  f[0] = __uint_as_float(u.x << 16); f[1] = __uint_as_float(u.x & 0xffff0000u);
  f[2] = __uint_as_float(u.y << 16); f[3] = __uint_as_float(u.y & 0xffff0000u);
}

// ---------- dtype-polymorphic loads (template = pointer holds fp32) ----------
template <bool F>
__device__ __forceinline__ void load8(const void* p, size_t idx, float* f) {
  if constexpr (F) {
    const float4* q = (const float4*)((const float*)p + idx);
    float4 a = q[0], b = q[1];
    f[0] = a.x; f[1] = a.y; f[2] = a.z; f[3] = a.w;
    f[4] = b.x; f[5] = b.y; f[6] = b.z; f[7] = b.w;
  } else {
    unpack8(*(const uint4*)((const u16*)p + idx), f);
  }
}
template <bool F>
__device__ __forceinline__ void load4(const void* p, size_t idx, float* f) {
  if constexpr (F) {
    float4 a = *(const float4*)((const float*)p + idx);
    f[0] = a.x; f[1] = a.y; f[2] = a.z; f[3] = a.w;
  } else {
    unpack4(*(const uint2*)((const u16*)p + idx), f);
  }
}
template <bool F>
__device__ __forceinline__ float load1(const void* p, size_t idx) {
  if constexpr (F) return ((const float*)p)[idx];
  else return bf2f(((const u16*)p)[idx]);
}

// ---------- async global -> LDS, 16B per lane ----------
__device__ __forceinline__ void gl2lds16(const void* g, void* l) {
  __builtin_amdgcn_global_load_lds(
      (const __attribute__((address_space(1))) void*)g,
      (__attribute__((address_space(3))) void*)l, 16, 0, 0);
}

// ---------- dtype detect: flag=1 -> inputs are fp32 ----------
__global__ void detect_dtype(const void* __restrict__ x, int* __restrict__ flag) {
  if (threadIdx.x == 0 && blockIdx.x == 0) {
    const u32* p = (const u32*)x;
    int sane = 0;
    for (int i = 0; i < 256; ++i) {
      u32 e = (p[i] >> 7) & 0xFFu;
      sane += (e >= 100u && e <= 150u) ? 1 : 0;
    }
    *flag = (sane < 192) ? 1 : 0;
  }
}

// ---------- diagnostic ----------
__global__ void signal_ws(u16* __restrict__ out, int n) {
  int i = blockIdx.x * 256 + threadIdx.x;
  if (i < n) out[i] = 0x42C8;  // bf16 100.0
}

#define SM_SCALE 0.08838834764831843f
// SM_SCALE * log2(e): Q pre-scale so softmax is a bare exp2
#define QSC 0.12751743f

// ============================================================================
// =========================== FAST PATH (needs 64 MiB ws) ====================
// ============================================================================

// ---------- K0: convert qkv weights+bias to bf16 (single launch, x8 vec) ----
__global__ void __launch_bounds__(256) wconv_rt(const void* __restrict__ qkvw,
                                                const void* __restrict__ qkvb,
                                                u16* __restrict__ dst,
                                                const int* __restrict__ flag) {
  const bool F = (flag[0] != 0);
  int i = (blockIdx.x * 256 + threadIdx.x) * 8;
  if (i >= 787968) return;
  if (!F) {
    uint4 v = (i < 786432) ? *(const uint4*)((const u16*)qkvw + i)
                           : *(const uint4*)((const u16*)qkvb + (i - 786432));
    *(uint4*)(dst + i) = v;
  } else {
    const float* src = (i < 786432) ? ((const float*)qkvw + i)
                                    : ((const float*)qkvb + (i - 786432));
    float f[8];
    float4 a = *(const float4*)src, b = *(const float4*)(src + 4);
    f[0]=a.x; f[1]=a.y; f[2]=a.z; f[3]=a.w; f[4]=b.x; f[5]=b.y; f[6]=b.z; f[7]=b.w;
    u32 w0 = (u32)f2bf(f[0]) | ((u32)f2bf(f[1]) << 16);
    u32 w1 = (u32)f2bf(f[2]) | ((u32)f2bf(f[3]) << 16);
    u32 w2 = (u32)f2bf(f[4]) | ((u32)f2bf(f[5]) << 16);
    u32 w3 = (u32)f2bf(f[6]) | ((u32)f2bf(f[7]) << 16);
    *(uint4*)(dst + i) = make_uint4(w0, w1, w2, w3);
  }
}

// ---------- K1: GroupNorm (two-pass) -> normalized transposed xT[b][s][c] ---
// Tf double-buffered: ONE barrier per 64-token chunk (read(c) -> barrier(c+1)
// -> write(c+2) into the same buffer; the intervening barrier orders every
// read-before-rewrite pair).
template <bool F>
__device__ __forceinline__ void gn_norm_body(
    const void* __restrict__ x, const void* __restrict__ gamma,
    const void* __restrict__ beta, u16* __restrict__ xT,
    int g, int b, int tid,
    float* ssum, float* ssq, float* scb, float* bsb, float (*Tf)[64][65]) {
  const size_t base = (size_t)(b * 512 + g * 64) * 1024;
  float sum = 0.f, sq = 0.f;
  for (int i = tid; i < 8192; i += 256) {
    float f[8]; load8<F>(x, base + (size_t)i * 8, f);
#pragma unroll
    for (int m = 0; m < 8; ++m) { sum += f[m]; sq += f[m] * f[m]; }
  }
  ssum[tid] = sum; ssq[tid] = sq; __syncthreads();
  for (int off = 128; off > 0; off >>= 1) {
    if (tid < off) { ssum[tid] += ssum[tid + off]; ssq[tid] += ssq[tid + off]; }
    __syncthreads();
  }
  if (tid < 64) {
    float mu  = ssum[0] * (1.f / 65536.f);
    float var = ssq[0] * (1.f / 65536.f) - mu * mu;
    float s = load1<F>(gamma, g * 64 + tid) * rsqrtf(var + 1e-5f);
    scb[tid] = s;
    bsb[tid] = load1<F>(beta, g * 64 + tid) - mu * s;
  }
  __syncthreads();

  for (int s0 = 0; s0 < 1024; s0 += 64) {
    const int pb = (s0 >> 6) & 1;
#pragma unroll
    for (int half = 0; half < 2; ++half) {
      int idx = tid + half * 256;
      int c_loc = idx >> 3, s8 = (idx & 7) * 8;
      float f[8];
      load8<F>(x, base + (size_t)c_loc * 1024 + s0 + s8, f);
      float sm = scb[c_loc], ba = bsb[c_loc];
#pragma unroll
      for (int m = 0; m < 8; ++m) Tf[pb][s8 + m][c_loc] = f[m] * sm + ba;
    }
    __syncthreads();
#pragma unroll
    for (int half = 0; half < 2; ++half) {
      int idx = tid + half * 256;
      int s_loc = idx >> 3, c8 = (idx & 7) * 8;
      u32 pk[4];
#pragma unroll
      for (int m = 0; m < 4; ++m)
        pk[m] = (u32)f2bf(Tf[pb][s_loc][c8 + 2 * m]) |
                ((u32)f2bf(Tf[pb][s_loc][c8 + 2 * m + 1]) << 16);
      *(uint4*)(xT + (size_t)(b * 1024 + s0 + s_loc) * 512 + g * 64 + c8) =
          make_uint4(pk[0], pk[1], pk[2], pk[3]);
    }
    // no trailing barrier: next chunk writes the other Tf buffer
  }
}

__global__ void __launch_bounds__(256) gn_norm_rt(const void* __restrict__ x,
                                                  const void* __restrict__ gamma,
                                                  const void* __restrict__ beta,
                                                  u16* __restrict__ xT,
                                                  const int* __restrict__ flag) {
  __shared__ float ssum[256], ssq[256], scb[64], bsb[64];
  __shared__ float Tf[2][64][65];
  const int g = blockIdx.x, b = blockIdx.y, tid = threadIdx.x;
  if (flag[0] != 0) gn_norm_body<true >(x, gamma, beta, xT, g, b, tid, ssum, ssq, scb, bsb, Tf);
  else              gn_norm_body<false>(x, gamma, beta, xT, g, b, tid, ssum, ssq, scb, bsb, Tf);
}

// ---------- K2: merged qk + v MFMA GEMM (r3-proven config) ------------------
// A/B HISTORY on this kernel:
//   r3: single-buf, natural blockIdx map, bounds(256,4)  -> < 52.8 us
//   r5: dbuf + XCD batch-swizzle, bounds(256,2)          ->   60.9 us
//   r6: single-buf + XCD batch-swizzle, bounds(256,4)    ->   64.1 us
// => the SWIZZLE is the regression (FETCH dropped 27.6->22.6 MB but time
// rose). The natural map already has the better locality: blockIdx.x is
// fastest => each XCD owns a FIXED n-column, so its 128 KB weight B-panel
// stays L2-hot while A streams; my batch-swizzle traded that for a 3.5 MB
// batch working set that 6 MB of streaming writes kept evicting. REVERTED
// to the exact r3 mapping.
// Grid (8, 12, 16): y<8 = qk role (D[s][o], Q cols pre-scaled), y>=8 = v
// role (D[c][s]). Block-uniform selects. LDS unpadded flat [128][64] u16,
// XOR chunk swizzle realized on the global SOURCE address.
__global__ void __launch_bounds__(256, 4)
gemm_qkv(const u16* __restrict__ xT, const u16* __restrict__ wbf,
         u16* __restrict__ qkT, u16* __restrict__ Vbuf) {
  const bool vrole = (blockIdx.y >= 8);
  const int n0 = blockIdx.x * 128;
  const int m0 = (vrole ? (int)blockIdx.y - 8 : (int)blockIdx.y) * 128;
  const int b  = blockIdx.z;
  __shared__ __align__(16) u16 At[8192];   // 128 rows x 64 u16 (128 B)
  __shared__ __align__(16) u16 Bt[8192];
  const int tid = threadIdx.x;
  const int w = tid >> 6, lane = tid & 63;
  const int lo = lane & 31, hi = lane >> 5;
  const int wm = w >> 1, wn = w & 1;
  const u16* bias = wbf + 786432;
  const u16* Ab = vrole ? (wbf + 524288) : (xT + (size_t)b * 524288);
  const u16* Bb = vrole ? (xT + (size_t)b * 524288) : wbf;
  u16* outp = vrole ? (Vbuf + (size_t)b * 524288) : (qkT + (size_t)b * 1048576);
  const int srow = lane >> 3, spc = lane & 7;

  f32x16 cA[2][2];
#pragma unroll
  for (int i = 0; i < 2; ++i)
#pragma unroll
    for (int j = 0; j < 2; ++j)
#pragma unroll
      for (int r = 0; r < 16; ++r) cA[i][j][r] = 0.f;

  for (int kt = 0; kt < 8; ++kt) {
    const int kb = kt * 64;
#pragma unroll
    for (int c = 0; c < 4; ++c) {
      int grp = w * 4 + c;                 // 16 groups of 1 KB
      int row = grp * 8 + srow;            // 0..127
      int lc  = spc ^ (row & 7);
      gl2lds16(Ab + (size_t)(m0 + row) * 512 + kb + lc * 8, &At[grp * 512]);
      gl2lds16(Bb + (size_t)(n0 + row) * 512 + kb + lc * 8, &Bt[grp * 512]);
    }
    __syncthreads();
#pragma unroll
    for (int k16 = 0; k16 < 4; ++k16) {
      const int lc = k16 * 2 + hi;
      const int rA0 = wm * 64 + lo,  rA1 = rA0 + 32;
      const int rB0 = wn * 64 + lo,  rB1 = rB0 + 32;
      bf16x8 a0 = *(const bf16x8*)&At[rA0 * 64 + ((lc ^ (rA0 & 7)) << 3)];
      bf16x8 a1 = *(const bf16x8*)&At[rA1 * 64 + ((lc ^ (rA1 & 7)) << 3)];
      bf16x8 b0 = *(const bf16x8*)&Bt[rB0 * 64 + ((lc ^ (rB0 & 7)) << 3)];
      bf16x8 b1 = *(const bf16x8*)&Bt[rB1 * 64 + ((lc ^ (rB1 & 7)) << 3)];
      cA[0][0] = MFMA32(a0, b0, cA[0][0]);
      cA[0][1] = MFMA32(a0, b1, cA[0][1]);
      cA[1][0] = MFMA32(a1, b0, cA[1][0]);
      cA[1][1] = MFMA32(a1, b1, cA[1][1]);
    }
    __syncthreads();
  }

  float bcol[2] = {0.f, 0.f};
  if (!vrole) {
    bcol[0] = bf2f(bias[n0 + wn * 64 + lo]);
    bcol[1] = bf2f(bias[n0 + wn * 64 + 32 + lo]);
  }
#pragma unroll
  for (int mt = 0; mt < 2; ++mt)
#pragma unroll
    for (int nt = 0; nt < 2; ++nt) {
      const int nbase = n0 + wn * 64 + nt * 32;
#pragma unroll
      for (int r = 0; r < 16; ++r) {
        int m = m0 + wm * 64 + mt * 32 + (r & 3) + 8 * (r >> 2) + 4 * hi;
        int n = nbase + lo;
        float v = cA[mt][nt][r];
        if (!vrole) {
          v += bcol[nt];
          if (nbase < 512) v *= QSC;
        } else {
          v += bf2f(bias[1024 + m]);
        }
        outp[(size_t)m * 1024 + n] = f2bf(v);
      }
    }
}

// ---------- K2b (proj): runtime-flag MFMA GEMM (VGPR staging) ---------------
// D[o][s] = projW[o].aout[s] + proj_b[o] + x[b][o][s]; out dtype follows input.
template <bool F>
__device__ __forceinline__ void proj_body(const void* __restrict__ A,
                                          const u16* __restrict__ B,
                                          const void* __restrict__ bias,
                                          const void* __restrict__ resid,
                                          void* __restrict__ outp,
                                          int n0, int m0, int b, int tid,
                                          u16 (*At)[72], u16 (*Bt)[72]) {
  const int w = tid >> 6, lane = tid & 63;
  const int lo = lane & 31, hi = lane >> 5;
  const int wm = w >> 1, wn = w & 1;
  const size_t bBase = (size_t)b * 524288;

  f32x16 cA[2][2];
#pragma unroll
  for (int i = 0; i < 2; ++i)
#pragma unroll
    for (int j = 0; j < 2; ++j)
#pragma unroll
      for (int r = 0; r < 16; ++r) cA[i][j][r] = 0.f;

  for (int kt = 0; kt < 8; ++kt) {
#pragma unroll
    for (int i = 0; i < 4; ++i) {
      int idx = tid + i * 256;
      int row = idx >> 3, kc = (idx & 7) * 8;
      int k = kt * 64 + kc;
      {  // A = proj weights (fp32 if F else bf16)
        if constexpr (F) {
          float f[8]; load8<true>(A, (size_t)(m0 + row) * 512 + k, f);
          u32 w0 = (u32)f2bf(f[0]) | ((u32)f2bf(f[1]) << 16);
          u32 w1 = (u32)f2bf(f[2]) | ((u32)f2bf(f[3]) << 16);
          u32 w2 = (u32)f2bf(f[4]) | ((u32)f2bf(f[5]) << 16);
          u32 w3 = (u32)f2bf(f[6]) | ((u32)f2bf(f[7]) << 16);
          *(uint4*)&At[row][kc] = make_uint4(w0, w1, w2, w3);
        } else {
          *(uint4*)&At[row][kc] =
              *(const uint4*)((const u16*)A + (size_t)(m0 + row) * 512 + k);
        }
      }
      *(uint4*)&Bt[row][kc] =
          *(const uint4*)(B + bBase + (size_t)(n0 + row) * 512 + k);
    }
    __syncthreads();
#pragma unroll
    for (int k16 = 0; k16 < 4; ++k16) {
      const int ko = k16 * 16 + hi * 8;
      bf16x8 a0 = *(const bf16x8*)&At[wm * 64 + lo][ko];
      bf16x8 a1 = *(const bf16x8*)&At[wm * 64 + 32 + lo][ko];
      bf16x8 b0 = *(const bf16x8*)&Bt[wn * 64 + lo][ko];
      bf16x8 b1 = *(const bf16x8*)&Bt[wn * 64 + 32 + lo][ko];
      cA[0][0] = MFMA32(a0, b0, cA[0][0]);
      cA[0][1] = MFMA32(a0, b1, cA[0][1]);
      cA[1][0] = MFMA32(a1, b0, cA[1][0]);
      cA[1][1] = MFMA32(a1, b1, cA[1][1]);
    }
    __syncthreads();
  }

#pragma unroll
  for (int mt = 0; mt < 2; ++mt)
#pragma unroll
    for (int nt = 0; nt < 2; ++nt) {
#pragma unroll
      for (int r = 0; r < 16; ++r) {
        int m = m0 + wm * 64 + mt * 32 + (r & 3) + 8 * (r >> 2) + 4 * hi;
        int n = n0 + wn * 64 + nt * 32 + lo;
        float v = cA[mt][nt][r];
        v += load1<F>(bias, m);
        v += load1<F>(resid, bBase + (size_t)m * 1024 + n);
        size_t off = bBase + (size_t)m * 1024 + n;
        if constexpr (F) ((float*)outp)[off] = v;
        else             ((u16*)outp)[off] = f2bf(v);
      }
    }
}

__global__ void __launch_bounds__(256, 4)
proj_rt(const void* __restrict__ projw, const u16* __restrict__ aout,
        const void* __restrict__ projb, const void* __restrict__ x,
        void* __restrict__ outp, const int* __restrict__ flag) {
  __shared__ __align__(16) u16 At[128][72];
  __shared__ __align__(16) u16 Bt[128][72];
  const int n0 = blockIdx.x * 128, m0 = blockIdx.y * 128, b = blockIdx.z;
  if (flag[0] != 0) proj_body<true >(projw, aout, projb, x, outp, n0, m0, b, threadIdx.x, At, Bt);
  else              proj_body<false>(projw, aout, projb, x, outp, n0, m0, b, threadIdx.x, At, Bt);
}

// ---------- K3: MFMA flash attention v2 (proven config: no setprio) ---------
// qkT[b][s][o] (o<512: Q pre-scaled by QSC, 512..1024: K), V[b][c][s].
// aout[b][s][c] (=xT buffer). Grid (bh, qtile): the 8 q-blocks of one (b,h)
// land on one XCD already (64 % 8 == 0) — K/V L2-local by construction.
__global__ void __launch_bounds__(256, 2) attn4(const u16* __restrict__ qkT,
                                                const u16* __restrict__ V,
                                                u16* __restrict__ aout) {
  const int bh = blockIdx.x;
  const int q0 = blockIdx.y * 128;
  const int b = bh >> 2, h = bh & 3;
  const u16* qt = qkT + (size_t)b * 1048576;
  const u16* vb = V + (size_t)b * 524288 + (size_t)(h * 128) * 1024;
  // buf i at smem[i*16384]: K [64][128] | V (+8192) [128][64]
  __shared__ __align__(16) u16 smem[32768];
  const int tid = threadIdx.x;
  const int w = tid >> 6, lane = tid & 63;
  const int lo = lane & 31, hi = lane >> 5;

  // stage Q -> buf0
#pragma unroll
  for (int c = 0; c < 8; ++c) {
    int grp = w * 8 + c;
    int row = grp * 4 + (lane >> 4);
    int lc  = (lane & 15) ^ (row & 7);
    gl2lds16(qt + (size_t)(q0 + row) * 1024 + h * 128 + lc * 8, &smem[grp * 512]);
  }
  // stage K/V (kt=0) -> buf1
#pragma unroll
  for (int c = 0; c < 4; ++c) {
    int grp = w * 4 + c;
    { int row = grp * 4 + (lane >> 4);
      int lc  = (lane & 15) ^ (row & 7);
      gl2lds16(qt + (size_t)row * 1024 + 512 + h * 128 + lc * 8,
               &smem[16384 + grp * 512]); }
    { int row = grp * 8 + (lane >> 3);
      int lc  = (lane & 7) ^ (row & 7);
      gl2lds16(vb + (size_t)row * 1024 + lc * 8,
               &smem[16384 + 8192 + grp * 512]); }
  }
  __syncthreads();
  bf16x8 qf[8];
  {
    const int row = 32 * w + lo;
#pragma unroll
    for (int k16 = 0; k16 < 8; ++k16) {
      int lc = k16 * 2 + hi;
      qf[k16] = *(const bf16x8*)&smem[row * 128 + ((lc ^ (row & 7)) << 3)];
    }
  }
  __syncthreads();   // Q fragment reads complete before kt=1 stage hits buf0

  f32x16 o[4];
  float lp = 0.f;
#pragma unroll
  for (int dt = 0; dt < 4; ++dt)
#pragma unroll
    for (int r = 0; r < 16; ++r) o[dt][r] = 0.f;

  for (int kt = 0; kt < 16; ++kt) {
    const u16* rb = &smem[((kt & 1) ^ 1) << 14];
    u16* wbuf = &smem[(kt & 1) << 14];

    // stage kt+1 into the other buffer; waited only at this iteration's
    // trailing barrier (vmcnt drain overlaps all compute below)
    if (kt < 15) {
      const int k0n = (kt + 1) * 64;
#pragma unroll
      for (int c = 0; c < 4; ++c) {
        int grp = w * 4 + c;
        { int row = grp * 4 + (lane >> 4);
          int lc  = (lane & 15) ^ (row & 7);
          gl2lds16(qt + (size_t)(k0n + row) * 1024 + 512 + h * 128 + lc * 8,
                   wbuf + grp * 512); }
        { int row = grp * 8 + (lane >> 3);
          int lc  = (lane & 7) ^ (row & 7);
          gl2lds16(vb + (size_t)row * 1024 + k0n + lc * 8,
                   wbuf + 8192 + grp * 512); }
      }
    }

    // S^T = K Q (A = K rows = keys, B = Q cols = q):
    // lane (lo,hi): s0[r] = S[key=(r&3)+8(r>>2)+4hi][q=lo], s1: keys +32
    f32x16 s0, s1;
#pragma unroll
    for (int r = 0; r < 16; ++r) { s0[r] = 0.f; s1[r] = 0.f; }
#pragma unroll
    for (int k16 = 0; k16 < 8; ++k16) {
      const int lc = k16 * 2 + hi;
      const int r0 = lo, r1 = lo + 32;
      bf16x8 kf0 = *(const bf16x8*)&rb[r0 * 128 + ((lc ^ (r0 & 7)) << 3)];
      bf16x8 kf1 = *(const bf16x8*)&rb[r1 * 128 + ((lc ^ (r1 & 7)) << 3)];
      s0 = MFMA32(kf0, qf[k16], s0);
      s1 = MFMA32(kf1, qf[k16], s1);
    }

    // P = exp2(S) in-register; per-lane partial row-sum (q = lo)
#pragma unroll
    for (int r = 0; r < 16; ++r) {
      s0[r] = exp2f(s0[r]);
      s1[r] = exp2f(s1[r]);
      lp += s0[r] + s1[r];
    }

    // Pack P into PV A-frags: pa[t] = P[q=lo][16t + 8*hi .. +7].
    bf16x8 pa[4];
#define MKPA(ps, rb0, dst) do {                                               \
      u32 qa0, qa1, qb0, qb1;                                                 \
      asm("v_cvt_pk_bf16_f32 %0, %1, %2" : "=v"(qa0)                          \
          : "v"((ps)[(rb0) + 0]), "v"((ps)[(rb0) + 1]));                      \
      asm("v_cvt_pk_bf16_f32 %0, %1, %2" : "=v"(qa1)                          \
          : "v"((ps)[(rb0) + 2]), "v"((ps)[(rb0) + 3]));                      \
      asm("v_cvt_pk_bf16_f32 %0, %1, %2" : "=v"(qb0)                          \
          : "v"((ps)[(rb0) + 4]), "v"((ps)[(rb0) + 5]));                      \
      asm("v_cvt_pk_bf16_f32 %0, %1, %2" : "=v"(qb1)                          \
          : "v"((ps)[(rb0) + 6]), "v"((ps)[(rb0) + 7]));                      \
      u32x2 r0 = __builtin_amdgcn_permlane32_swap(qa0, qb0, false, false);    \
      u32x2 r1 = __builtin_amdgcn_permlane32_swap(qa1, qb1, false, false);    \
      union { u32 u[4]; bf16x8 v8; } pk_;                                     \
      pk_.u[0] = r0[0]; pk_.u[1] = r1[0]; pk_.u[2] = r0[1]; pk_.u[3] = r1[1]; \
      dst = pk_.v8;                                                           \
    } while (0)
    MKPA(s0, 0, pa[0]);
    MKPA(s0, 8, pa[1]);
    MKPA(s1, 0, pa[2]);
    MKPA(s1, 8, pa[3]);
#undef MKPA

    // O += P V
#pragma unroll
    for (int t = 0; t < 4; ++t) {
      const int lc = t * 2 + hi;
#pragma unroll
      for (int dt = 0; dt < 4; ++dt) {
        const int row = dt * 32 + lo;
        bf16x8 bv = *(const bf16x8*)&rb[8192 + row * 64 + ((lc ^ (row & 7)) << 3)];
        o[dt] = MFMA32(pa[t], bv, o[dt]);
      }
    }
    __syncthreads();  // reads of rb done by all waves + stage into wbuf landed
  }

  // full row-sum across the hi pair; linv lives at lane lo = q-row
  float linv = 1.f / (lp + __shfl_xor(lp, 32));
#pragma unroll
  for (int r = 0; r < 16; ++r) {
    int pat = (r & 3) + 8 * (r >> 2) + 4 * hi;
    float lr = __shfl(linv, pat);   // broadcast from lane pat (q = pat)
    int q = q0 + 32 * w + pat;
    size_t base = (size_t)(b * 1024 + q) * 512 + h * 128;
    aout[base +  0 + lo] = f2bf(o[0][r] * lr);
    aout[base + 32 + lo] = f2bf(o[1][r] * lr);
    aout[base + 64 + lo] = f2bf(o[2][r] * lr);
    aout[base + 96 + lo] = f2bf(o[3][r] * lr);
  }
}

// ============================================================================
// ====================== FALLBACK PATH (round-4, proven) =====================
// ============================================================================

template <bool F>
__global__ void __launch_bounds__(256) gn_stats(const void* __restrict__ x,
                                                const void* __restrict__ gamma,
                                                const void* __restrict__ beta,
                                                float* __restrict__ sc,
                                                float* __restrict__ bs,
                                                const int* __restrict__ flag) {
  if ((flag[0] != 0) != F) return;
  const int g = blockIdx.x, b = blockIdx.y;
  const int tid = threadIdx.x;
  const size_t base = (size_t)(b * 512 + g * 64) * 1024;
  float sum = 0.f, sq = 0.f;
  for (int i = tid; i < 8192; i += 256) {
    float f[8]; load8<F>(x, base + (size_t)i * 8, f);
#pragma unroll
    for (int m = 0; m < 8; ++m) { sum += f[m]; sq += f[m] * f[m]; }
  }
  __shared__ float ssum[256], ssq[256];
  ssum[tid] = sum; ssq[tid] = sq; __syncthreads();
  for (int off = 128; off > 0; off >>= 1) {
    if (tid < off) { ssum[tid] += ssum[tid + off]; ssq[tid] += ssq[tid + off]; }
    __syncthreads();
  }
  if (tid < 64) {
    float mu  = ssum[0] * (1.f / 65536.f);
    float var = ssq[0] * (1.f / 65536.f) - mu * mu;
    int c = g * 64 + tid;
    float s = load1<F>(gamma, c) * rsqrtf(var + 1e-5f);
    sc[b * 512 + c] = s;
    bs[b * 512 + c] = load1<F>(beta, c) - mu * s;
  }
}

template <bool F, bool BEXT, bool FOUT>
__global__ void __launch_bounds__(256) gemm64(const void* __restrict__ A,
                                              const void* __restrict__ B,
                                              const float* __restrict__ sc,
                                              const float* __restrict__ bs,
                                              const void* __restrict__ bias,
                                              const void* __restrict__ resid,
                                              void* __restrict__ outp,
                                              int mrows, int donorm, int bstride,
                                              const int* __restrict__ flag) {
  if ((flag[0] != 0) != F) return;
  const int s0 = blockIdx.x * 64;
  const int o0 = blockIdx.y * 64;
  const int b  = blockIdx.z;
  __shared__ __align__(16) float At[64][36];
  __shared__ __align__(16) float Bt[64][36];
  const int tid = threadIdx.x;
  const int ty = tid >> 4, tx = tid & 15;
  const int i0 = ty * 4, j0 = tx * 4;
  const int arow = tid >> 2, akc = (tid & 3) * 8;
  const int brow = tid >> 3, bnc = (tid & 7) * 8;
  float acc[4][4] = {};

  for (int kt = 0; kt < 512; kt += 32) {
    float af[8];
    load8<F>(A, (size_t)(o0 + arow) * 512 + akc + kt, af);
    *(float4*)&At[arow][akc]     = make_float4(af[0], af[1], af[2], af[3]);
    *(float4*)&At[arow][akc + 4] = make_float4(af[4], af[5], af[6], af[7]);
    const int c = kt + brow;
    float bf[8];
    load8<(BEXT && F)>(B, (size_t)(b * bstride + c) * 1024 + s0 + bnc, bf);
    float smul = 1.f, badd = 0.f;
    if (donorm) { smul = sc[b * 512 + c]; badd = bs[b * 512 + c]; }
#pragma unroll
    for (int m = 0; m < 8; ++m) Bt[bnc + m][brow] = bf[m] * smul + badd;
    __syncthreads();
#pragma unroll
    for (int kq = 0; kq < 8; ++kq) {
      float4 a0 = *(const float4*)&At[i0 + 0][kq * 4];
      float4 a1 = *(const float4*)&At[i0 + 1][kq * 4];
      float4 a2 = *(const float4*)&At[i0 + 2][kq * 4];
      float4 a3 = *(const float4*)&At[i0 + 3][kq * 4];
      float4 c0 = *(const float4*)&Bt[j0 + 0][kq * 4];
      float4 c1 = *(const float4*)&Bt[j0 + 1][kq * 4];
      float4 c2 = *(const float4*)&Bt[j0 + 2][kq * 4];
      float4 c3 = *(const float4*)&Bt[j0 + 3][kq * 4];
#define DOT4(ii, jj, AV, CV) acc[ii][jj] += AV.x * CV.x + AV.y * CV.y + AV.z * CV.z + AV.w * CV.w;
      DOT4(0,0,a0,c0) DOT4(0,1,a0,c1) DOT4(0,2,a0,c2) DOT4(0,3,a0,c3)
      DOT4(1,0,a1,c0) DOT4(1,1,a1,c1) DOT4(1,2,a1,c2) DOT4(1,3,a1,c3)
      DOT4(2,0,a2,c0) DOT4(2,1,a2,c1) DOT4(2,2,a2,c2) DOT4(2,3,a2,c3)
      DOT4(3,0,a3,c0) DOT4(3,1,a3,c1) DOT4(3,2,a3,c2) DOT4(3,3,a3,c3)
#undef DOT4
    }
    __syncthreads();
  }
#pragma unroll
  for (int ii = 0; ii < 4; ++ii) {
    const int o = o0 + i0 + ii;
    const float bb = load1<F>(bias, o);
    float v[4];
#pragma unroll
    for (int jj = 0; jj < 4; ++jj) v[jj] = acc[ii][jj] + bb;
    if (resid) {
      float xf[4];
      load4<F>(resid, (size_t)(b * 512 + o) * 1024 + s0 + j0, xf);
#pragma unroll
      for (int jj = 0; jj < 4; ++jj) v[jj] += xf[jj];
    }
    const size_t ooff = (size_t)(b * mrows + o) * 1024 + s0 + j0;
    if constexpr (FOUT) {
      *(float4*)((float*)outp + ooff) = make_float4(v[0], v[1], v[2], v[3]);
    } else {
      uint2 pk;
      pk.x = (u32)f2bf(v[0]) | ((u32)f2bf(v[1]) << 16);
      pk.y = (u32)f2bf(v[2]) | ((u32)f2bf(v[3]) << 16);
      *(uint2*)((u16*)outp + ooff) = pk;
    }
  }
}

__global__ void __launch_bounds__(256, 2) attn_old(u16* __restrict__ qkv) {
  const int q0 = blockIdx.x * 128;
  const int bh = blockIdx.y;
  const int b = bh >> 2, h = bh & 3;
  u16* qp = qkv + (size_t)(b * 1536 + h * 128) * 1024;
  const u16* kp = qp + (size_t)512 * 1024;
  const u16* vp = qp + (size_t)1024 * 1024;
  __shared__ __align__(16) u16 Qt[128][136];
  __shared__ __align__(16) u16 Kt[32][136];
  __shared__ __align__(16) u16 Vt[128][40];
  __shared__ __align__(16) u16 Pt[128][40];
  const int tid = threadIdx.x;
  const int w = tid >> 6, lane = tid & 63;
  const int lo = lane & 31, hi = lane >> 5;

  for (int idx = tid; idx < 2048; idx += 256) {
    int d = idx >> 4, s8 = (idx & 15) * 8;
    uint4 qv = *(const uint4*)(qp + (size_t)d * 1024 + q0 + s8);
    const u16* qs = (const u16*)&qv;
#pragma unroll
    for (int m = 0; m < 8; ++m) Qt[s8 + m][d] = qs[m];
  }
  __syncthreads();
  bf16x8 qf[8];
#pragma unroll
  for (int kq = 0; kq < 8; ++kq)
    qf[kq] = *(const bf16x8*)&Qt[32 * w + lo][kq * 16 + hi * 8];

  f32x16 o0, o1, o2, o3;
  float lp[16];
#pragma unroll
  for (int r = 0; r < 16; ++r) { o0[r] = 0.f; o1[r] = 0.f; o2[r] = 0.f; o3[r] = 0.f; lp[r] = 0.f; }

  for (int kt = 0; kt < 32; ++kt) {
    const int k0 = kt * 32;
    __syncthreads();
    for (int idx = tid; idx < 512; idx += 256) {
      int d = idx >> 2, s8 = (idx & 3) * 8;
      uint4 kv = *(const uint4*)(kp + (size_t)d * 1024 + k0 + s8);
      const u16* ks = (const u16*)&kv;
#pragma unroll
      for (int m = 0; m < 8; ++m) Kt[s8 + m][d] = ks[m];
      *(uint4*)&Vt[d][s8] = *(const uint4*)(vp + (size_t)d * 1024 + k0 + s8);
    }
    __syncthreads();
    f32x16 acc;
#pragma unroll
    for (int r = 0; r < 16; ++r) acc[r] = 0.f;
#pragma unroll
    for (int kq = 0; kq < 8; ++kq) {
      bf16x8 bq = *(const bf16x8*)&Kt[lo][kq * 16 + hi * 8];
      acc = MFMA32(qf[kq], bq, acc);
    }
#pragma unroll
    for (int r = 0; r < 16; ++r) {
      float pe = __expf(acc[r] * SM_SCALE);
      lp[r] += pe;
      int row = (r & 3) + 8 * (r >> 2) + 4 * hi;
      Pt[32 * w + row][lo] = f2bf(pe);
    }
    __syncthreads();
#pragma unroll
    for (int kq2 = 0; kq2 < 2; ++kq2) {
      bf16x8 a2 = *(const bf16x8*)&Pt[32 * w + lo][kq2 * 16 + hi * 8];
      bf16x8 b0 = *(const bf16x8*)&Vt[ 0 + lo][kq2 * 16 + hi * 8];
      bf16x8 b1 = *(const bf16x8*)&Vt[32 + lo][kq2 * 16 + hi * 8];
      bf16x8 b2 = *(const bf16x8*)&Vt[64 + lo][kq2 * 16 + hi * 8];
      bf16x8 b3 = *(const bf16x8*)&Vt[96 + lo][kq2 * 16 + hi * 8];
      o0 = MFMA32(a2, b0, o0);
      o1 = MFMA32(a2, b1, o1);
      o2 = MFMA32(a2, b2, o2);
      o3 = MFMA32(a2, b3, o3);
    }
  }
#pragma unroll
  for (int r = 0; r < 16; ++r) {
    float su = lp[r];
    su += __shfl_xor(su, 1);  su += __shfl_xor(su, 2);
    su += __shfl_xor(su, 4);  su += __shfl_xor(su, 8);
    su += __shfl_xor(su, 16);
    float linv = 1.f / su;
    int row = (r & 3) + 8 * (r >> 2) + 4 * hi;
    int q = q0 + 32 * w + row;
    size_t base = (size_t)(b * 1536 + h * 128) * 1024 + q;
    qkv[base + (size_t)( 0 + lo) * 1024] = f2bf(o0[r] * linv);
    qkv[base + (size_t)(32 + lo) * 1024] = f2bf(o1[r] * linv);
    qkv[base + (size_t)(64 + lo) * 1024] = f2bf(o2[r] * linv);
    qkv[base + (size_t)(96 + lo) * 1024] = f2bf(o3[r] * linv);
  }
}

// ---------- launch ----------
extern "C" void kernel_launch(void* const* d_in, const int* in_sizes, int n_in,
                              void* d_out, int out_size, void* d_ws, size_t ws_size,
                              hipStream_t stream) {
  const void* x     = d_in[0];
  const void* gamma = d_in[1];
  const void* beta  = d_in[2];
  const void* qkvw  = d_in[3];
  const void* qkvb  = d_in[4];
  const void* projw = d_in[5];
  const void* projb = d_in[6];

  char* ws = (char*)d_ws;
  const size_t MB = 1024 * 1024;
  const size_t FAST_NEED = 64 * MB + 64;
  const size_t OLD_NEED  = 48 * MB + 256 + 2 * 16 * 512 * 4;

  if (ws_size >= FAST_NEED) {
    u16* xT   = (u16*)ws;                 // [16][1024][512] normalized; reused as aout
    u16* qkT  = (u16*)(ws + 16 * MB);     // [16][1024][1024] (Q'|K per token row)
    u16* Vbuf = (u16*)(ws + 48 * MB);     // [16][512][1024]
    int* flag = (int*)(ws + 64 * MB);
    u16* wbf  = (u16*)d_out;              // bf16 qkv weights+bias (1.5 MB);
                                          // dead region until proj overwrites

    detect_dtype<<<1, 64, 0, stream>>>(x, flag);
    wconv_rt<<<385, 256, 0, stream>>>(qkvw, qkvb, wbf, flag);
    gn_norm_rt<<<dim3(8, 16), 256, 0, stream>>>(x, gamma, beta, xT, flag);

    // merged qk + v GEMM (single-buffer, natural block map — r3 config)
    gemm_qkv<<<dim3(8, 12, 16), 256, 0, stream>>>(xT, wbf, qkT, Vbuf);

    attn4<<<dim3(64, 8), 256, 0, stream>>>(qkT, Vbuf, xT);  // aout overwrites xT

    // proj: D[o][s] = projW[o][:] . aout[s][:] + proj_b[o] + x
    proj_rt<<<dim3(8, 4, 16), 256, 0, stream>>>(projw, xT, projb, x, d_out, flag);
    return;
  }

  if (ws_size < OLD_NEED) {
    signal_ws<<<(out_size + 255) / 256, 256, 0, stream>>>((u16*)d_out, out_size);
    return;
  }

  // ---- round-4 fallback ----
  const size_t QKV_BYTES = (size_t)16 * 1536 * 1024 * 2;
  u16* qkv  = (u16*)ws;
  int* flag = (int*)(ws + QKV_BYTES);
  float* sc = (float*)(ws + QKV_BYTES + 256);
  float* bs = sc + 16 * 512;

  detect_dtype<<<1, 64, 0, stream>>>(x, flag);
  gn_stats<false><<<dim3(8, 16), 256, 0, stream>>>(x, gamma, beta, sc, bs, flag);
  gn_stats<true ><<<dim3(8, 16), 256, 0, stream>>>(x, gamma, beta, sc, bs, flag);
  gemm64<false, true, false><<<dim3(16, 24, 16), 256, 0, stream>>>(
      qkvw, x, sc, bs, qkvb, nullptr, qkv, 1536, 1, 512, flag);
  gemm64<true, true, false><<<dim3(16, 24, 16), 256, 0, stream>>>(
      qkvw, x, sc, bs, qkvb, nullptr, qkv, 1536, 1, 512, flag);
  attn_old<<<dim3(8, 64), 256, 0, stream>>>(qkv);
  gemm64<false, false, false><<<dim3(16, 8, 16), 256, 0, stream>>>(
      projw, qkv, sc, bs, projb, x, d_out, 512, 0, 1536, flag);
  gemm64<true, false, true><<<dim3(16, 8, 16), 256, 0, stream>>>(
      projw, qkv, sc, bs, projb, x, d_out, 512, 0, 1536, flag);
}

// Round 8
// 237.749 us; speedup vs baseline: 1.1046x; 1.1046x over previous
//
#include <hip/hip_runtime.h>

typedef unsigned short u16;
typedef unsigned int   u32;

typedef __attribute__((ext_vector_type(8)))  short bf16x8;
typedef __attribute__((ext_vector_type(16))) float f32x16;
typedef __attribute__((ext_vector_type(2)))  unsigned int u32x2;
#define MFMA32(a, b, c) __builtin_amdgcn_mfma_f32_32x32x16_bf16(a, b, c, 0, 0, 0)

// ---------- bf16 helpers ----------
__device__ __forceinline__ float bf2f(u16 h) { return __uint_as_float(((u32)h) << 16); }
__device__ __forceinline__ u16 f2bf(float f) {
  u32 u = __float_as_uint(f);
  u += 0x7fffu + ((u >> 16) & 1u);   // RNE
  return (u16)(u >> 16);
}
__device__ __forceinline__ void unpack8(uint4 u, float* f) {
  f[0] = __uint_as_float(u.x << 16); f[1] = __uint_as_float(u.x & 0xffff0000u);
  f[2] = __uint_as_float(u.y << 16); f[3] = __uint_as_float(u.y & 0xffff0000u);
  f[4] = __uint_as_float(u.z << 16); f[5] = __uint_as_float(u.z & 0xffff0000u);
  f[6] = __uint_as_float(u.w << 16); f[7] = __uint_as_float(u.w & 0xffff0000u);
}
__device__ __forceinline__ void unpack4(uint2 u, float* f) {
  f[0] = __uint_as_float(u.x << 16); f[1] = __uint_as_float(u.x & 0xffff0000u);
  f[2] = __uint_as_float(u.y << 16); f[3] = __uint_as_float(u.y & 0xffff0000u);
}

// ---------- dtype-polymorphic loads (template = pointer holds fp32) ----------
template <bool F>
__device__ __forceinline__ void load8(const void* p, size_t idx, float* f) {
  if constexpr (F) {
    const float4* q = (const float4*)((const float*)p + idx);
    float4 a = q[0], b = q[1];
    f[0] = a.x; f[1] = a.y; f[2] = a.z; f[3] = a.w;
    f[4] = b.x; f[5] = b.y; f[6] = b.z; f[7] = b.w;
  } else {
    unpack8(*(const uint4*)((const u16*)p + idx), f);
  }
}
template <bool F>
__device__ __forceinline__ void load4(const void* p, size_t idx, float* f) {
  if constexpr (F) {
    float4 a = *(const float4*)((const float*)p + idx);
    f[0] = a.x; f[1] = a.y; f[2] = a.z; f[3] = a.w;
  } else {
    unpack4(*(const uint2*)((const u16*)p + idx), f);
  }
}
template <bool F>
__device__ __forceinline__ float load1(const void* p, size_t idx) {
  if constexpr (F) return ((const float*)p)[idx];
  else return bf2f(((const u16*)p)[idx]);
}

// ---------- async global -> LDS, 16B per lane ----------
__device__ __forceinline__ void gl2lds16(const void* g, void* l) {
  __builtin_amdgcn_global_load_lds(
      (const __attribute__((address_space(1))) void*)g,
      (__attribute__((address_space(3))) void*)l, 16, 0, 0);
}

// ---------- dtype detect: flag=1 -> inputs are fp32 ----------
__global__ void detect_dtype(const void* __restrict__ x, int* __restrict__ flag) {
  if (threadIdx.x == 0 && blockIdx.x == 0) {
    const u32* p = (const u32*)x;
    int sane = 0;
    for (int i = 0; i < 256; ++i) {
      u32 e = (p[i] >> 7) & 0xFFu;
      sane += (e >= 100u && e <= 150u) ? 1 : 0;
    }
    *flag = (sane < 192) ? 1 : 0;
  }
}

// ---------- diagnostic ----------
__global__ void signal_ws(u16* __restrict__ out, int n) {
  int i = blockIdx.x * 256 + threadIdx.x;
  if (i < n) out[i] = 0x42C8;  // bf16 100.0
}

#define SM_SCALE 0.08838834764831843f
// SM_SCALE * log2(e): Q pre-scale so softmax is a bare exp2
#define QSC 0.12751743f

// ============================================================================
// =========================== FAST PATH (needs 64 MiB ws) ====================
// ============================================================================

// ---------- K0: convert qkv weights+bias to bf16 (single launch, x8 vec) ----
__global__ void __launch_bounds__(256) wconv_rt(const void* __restrict__ qkvw,
                                                const void* __restrict__ qkvb,
                                                u16* __restrict__ dst,
                                                const int* __restrict__ flag) {
  const bool F = (flag[0] != 0);
  int i = (blockIdx.x * 256 + threadIdx.x) * 8;
  if (i >= 787968) return;
  if (!F) {
    uint4 v = (i < 786432) ? *(const uint4*)((const u16*)qkvw + i)
                           : *(const uint4*)((const u16*)qkvb + (i - 786432));
    *(uint4*)(dst + i) = v;
  } else {
    const float* src = (i < 786432) ? ((const float*)qkvw + i)
                                    : ((const float*)qkvb + (i - 786432));
    float f[8];
    float4 a = *(const float4*)src, b = *(const float4*)(src + 4);
    f[0]=a.x; f[1]=a.y; f[2]=a.z; f[3]=a.w; f[4]=b.x; f[5]=b.y; f[6]=b.z; f[7]=b.w;
    u32 w0 = (u32)f2bf(f[0]) | ((u32)f2bf(f[1]) << 16);
    u32 w1 = (u32)f2bf(f[2]) | ((u32)f2bf(f[3]) << 16);
    u32 w2 = (u32)f2bf(f[4]) | ((u32)f2bf(f[5]) << 16);
    u32 w3 = (u32)f2bf(f[6]) | ((u32)f2bf(f[7]) << 16);
    *(uint4*)(dst + i) = make_uint4(w0, w1, w2, w3);
  }
}

// ---------- K1a: GroupNorm stats, 256-block split (r7: old gn_norm had only
// 128 blocks = HALF the CUs idle for a memory-bound pass) --------------------
// Grid (8 groups, 16 batches, 2 halves): each block reduces 32 ch x 1024
// positions -> partial (sum, sq) at part[(b*8+g)*4 + half*2].
template <bool F>
__device__ __forceinline__ void gn_stats2_body(const void* __restrict__ x,
                                               float* __restrict__ part,
                                               int g, int b, int half, int tid,
                                               float* ssum, float* ssq) {
  const size_t base = (size_t)(b * 512 + g * 64 + half * 32) * 1024;
  float sum = 0.f, sq = 0.f;
  for (int i = tid; i < 4096; i += 256) {
    float f[8]; load8<F>(x, base + (size_t)i * 8, f);
#pragma unroll
    for (int m = 0; m < 8; ++m) { sum += f[m]; sq += f[m] * f[m]; }
  }
  ssum[tid] = sum; ssq[tid] = sq; __syncthreads();
  for (int off = 128; off > 0; off >>= 1) {
    if (tid < off) { ssum[tid] += ssum[tid + off]; ssq[tid] += ssq[tid + off]; }
    __syncthreads();
  }
  if (tid == 0) {
    part[(b * 8 + g) * 4 + half * 2 + 0] = ssum[0];
    part[(b * 8 + g) * 4 + half * 2 + 1] = ssq[0];
  }
}

__global__ void __launch_bounds__(256) gn_stats2(const void* __restrict__ x,
                                                 float* __restrict__ part,
                                                 const int* __restrict__ flag) {
  __shared__ float ssum[256], ssq[256];
  const int g = blockIdx.x, b = blockIdx.y, half = blockIdx.z, tid = threadIdx.x;
  if (flag[0] != 0) gn_stats2_body<true >(x, part, g, b, half, tid, ssum, ssq);
  else              gn_stats2_body<false>(x, part, g, b, half, tid, ssum, ssq);
}

// ---------- K1b: GroupNorm apply + transpose -> xT[b][s][c], 256 blocks -----
// Grid (16 token-chunks of 64, 16 batches). Each block: derive per-channel
// scale/bias for all 512 ch from partials, then 8x (64ch x 64tok) transpose
// tiles through the dbuf'd Tf buffer (structure proven in rounds 4-7).
template <bool F>
__device__ __forceinline__ void gn_apply_body(
    const void* __restrict__ x, const void* __restrict__ gamma,
    const void* __restrict__ beta, const float* __restrict__ part,
    u16* __restrict__ xT, int chunk, int b, int tid,
    float* scb, float* bsb, float (*Tf)[64][65]) {
  const int s0 = chunk * 64;
  for (int c = tid; c < 512; c += 256) {
    int gg = c >> 6;
    const float* p = part + (b * 8 + gg) * 4;
    float sum = p[0] + p[2], sq = p[1] + p[3];
    float mu  = sum * (1.f / 65536.f);
    float var = sq * (1.f / 65536.f) - mu * mu;
    float s = load1<F>(gamma, c) * rsqrtf(var + 1e-5f);
    scb[c] = s;
    bsb[c] = load1<F>(beta, c) - mu * s;
  }
  __syncthreads();

  for (int gb = 0; gb < 8; ++gb) {
    const int pb = gb & 1;
#pragma unroll
    for (int half = 0; half < 2; ++half) {
      int idx = tid + half * 256;
      int c_loc = idx >> 3, s8 = (idx & 7) * 8;
      int c = gb * 64 + c_loc;
      float f[8];
      load8<F>(x, (size_t)(b * 512 + c) * 1024 + s0 + s8, f);
      float sm = scb[c], ba = bsb[c];
#pragma unroll
      for (int m = 0; m < 8; ++m) Tf[pb][s8 + m][c_loc] = f[m] * sm + ba;
    }
    __syncthreads();
#pragma unroll
    for (int half = 0; half < 2; ++half) {
      int idx = tid + half * 256;
      int s_loc = idx >> 3, c8 = (idx & 7) * 8;
      u32 pk[4];
#pragma unroll
      for (int m = 0; m < 4; ++m)
        pk[m] = (u32)f2bf(Tf[pb][s_loc][c8 + 2 * m]) |
                ((u32)f2bf(Tf[pb][s_loc][c8 + 2 * m + 1]) << 16);
      *(uint4*)(xT + (size_t)(b * 1024 + s0 + s_loc) * 512 + gb * 64 + c8) =
          make_uint4(pk[0], pk[1], pk[2], pk[3]);
    }
    // dbuf: no trailing barrier — next gb writes the other Tf buffer; the
    // NEXT load-phase barrier orders these reads before the gb+2 rewrite.
  }
}

__global__ void __launch_bounds__(256) gn_apply(const void* __restrict__ x,
                                                const void* __restrict__ gamma,
                                                const void* __restrict__ beta,
                                                const float* __restrict__ part,
                                                u16* __restrict__ xT,
                                                const int* __restrict__ flag) {
  __shared__ float scb[512], bsb[512];
  __shared__ float Tf[2][64][65];
  const int chunk = blockIdx.x, b = blockIdx.y, tid = threadIdx.x;
  if (flag[0] != 0) gn_apply_body<true >(x, gamma, beta, part, xT, chunk, b, tid, scb, bsb, Tf);
  else              gn_apply_body<false>(x, gamma, beta, part, xT, chunk, b, tid, scb, bsb, Tf);
}

// ---------- K2: merged qk + v MFMA GEMM (r3-proven config, FROZEN) ----------
// A/B HISTORY: natural map ~51.5 us (r3/r7) beats XCD-swizzle 64.1 (r6) and
// dbuf+swizzle 60.9 (r5). FETCH 71.6 MB @2.5 TB/s free-flowing beats 22.6 MB
// @1.2 TB/s serialized — locality tweaks on this kernel trade parallelism of
// misses for fewer misses and LOSE. Closed.
// Grid (8, 12, 16): y<8 = qk role (D[s][o], Q cols pre-scaled), y>=8 = v
// role (D[c][s]). Block-uniform selects. LDS unpadded flat [128][64] u16,
// XOR chunk swizzle realized on the global SOURCE address.
__global__ void __launch_bounds__(256, 4)
gemm_qkv(const u16* __restrict__ xT, const u16* __restrict__ wbf,
         u16* __restrict__ qkT, u16* __restrict__ Vbuf) {
  const bool vrole = (blockIdx.y >= 8);
  const int n0 = blockIdx.x * 128;
  const int m0 = (vrole ? (int)blockIdx.y - 8 : (int)blockIdx.y) * 128;
  const int b  = blockIdx.z;
  __shared__ __align__(16) u16 At[8192];   // 128 rows x 64 u16 (128 B)
  __shared__ __align__(16) u16 Bt[8192];
  const int tid = threadIdx.x;
  const int w = tid >> 6, lane = tid & 63;
  const int lo = lane & 31, hi = lane >> 5;
  const int wm = w >> 1, wn = w & 1;
  const u16* bias = wbf + 786432;
  const u16* Ab = vrole ? (wbf + 524288) : (xT + (size_t)b * 524288);
  const u16* Bb = vrole ? (xT + (size_t)b * 524288) : wbf;
  u16* outp = vrole ? (Vbuf + (size_t)b * 524288) : (qkT + (size_t)b * 1048576);
  const int srow = lane >> 3, spc = lane & 7;

  f32x16 cA[2][2];
#pragma unroll
  for (int i = 0; i < 2; ++i)
#pragma unroll
    for (int j = 0; j < 2; ++j)
#pragma unroll
      for (int r = 0; r < 16; ++r) cA[i][j][r] = 0.f;

  for (int kt = 0; kt < 8; ++kt) {
    const int kb = kt * 64;
#pragma unroll
    for (int c = 0; c < 4; ++c) {
      int grp = w * 4 + c;                 // 16 groups of 1 KB
      int row = grp * 8 + srow;            // 0..127
      int lc  = spc ^ (row & 7);
      gl2lds16(Ab + (size_t)(m0 + row) * 512 + kb + lc * 8, &At[grp * 512]);
      gl2lds16(Bb + (size_t)(n0 + row) * 512 + kb + lc * 8, &Bt[grp * 512]);
    }
    __syncthreads();
#pragma unroll
    for (int k16 = 0; k16 < 4; ++k16) {
      const int lc = k16 * 2 + hi;
      const int rA0 = wm * 64 + lo,  rA1 = rA0 + 32;
      const int rB0 = wn * 64 + lo,  rB1 = rB0 + 32;
      bf16x8 a0 = *(const bf16x8*)&At[rA0 * 64 + ((lc ^ (rA0 & 7)) << 3)];
      bf16x8 a1 = *(const bf16x8*)&At[rA1 * 64 + ((lc ^ (rA1 & 7)) << 3)];
      bf16x8 b0 = *(const bf16x8*)&Bt[rB0 * 64 + ((lc ^ (rB0 & 7)) << 3)];
      bf16x8 b1 = *(const bf16x8*)&Bt[rB1 * 64 + ((lc ^ (rB1 & 7)) << 3)];
      cA[0][0] = MFMA32(a0, b0, cA[0][0]);
      cA[0][1] = MFMA32(a0, b1, cA[0][1]);
      cA[1][0] = MFMA32(a1, b0, cA[1][0]);
      cA[1][1] = MFMA32(a1, b1, cA[1][1]);
    }
    __syncthreads();
  }

  float bcol[2] = {0.f, 0.f};
  if (!vrole) {
    bcol[0] = bf2f(bias[n0 + wn * 64 + lo]);
    bcol[1] = bf2f(bias[n0 + wn * 64 + 32 + lo]);
  }
#pragma unroll
  for (int mt = 0; mt < 2; ++mt)
#pragma unroll
    for (int nt = 0; nt < 2; ++nt) {
      const int nbase = n0 + wn * 64 + nt * 32;
#pragma unroll
      for (int r = 0; r < 16; ++r) {
        int m = m0 + wm * 64 + mt * 32 + (r & 3) + 8 * (r >> 2) + 4 * hi;
        int n = nbase + lo;
        float v = cA[mt][nt][r];
        if (!vrole) {
          v += bcol[nt];
          if (nbase < 512) v *= QSC;
        } else {
          v += bf2f(bias[1024 + m]);
        }
        outp[(size_t)m * 1024 + n] = f2bf(v);
      }
    }
}

// ---------- K2b (proj): runtime-flag MFMA GEMM (VGPR staging) ---------------
// D[o][s] = projW[o].aout[s] + proj_b[o] + x[b][o][s]; out dtype follows input.
template <bool F>
__device__ __forceinline__ void proj_body(const void* __restrict__ A,
                                          const u16* __restrict__ B,
                                          const void* __restrict__ bias,
                                          const void* __restrict__ resid,
                                          void* __restrict__ outp,
                                          int n0, int m0, int b, int tid,
                                          u16 (*At)[72], u16 (*Bt)[72]) {
  const int w = tid >> 6, lane = tid & 63;
  const int lo = lane & 31, hi = lane >> 5;
  const int wm = w >> 1, wn = w & 1;
  const size_t bBase = (size_t)b * 524288;

  f32x16 cA[2][2];
#pragma unroll
  for (int i = 0; i < 2; ++i)
#pragma unroll
    for (int j = 0; j < 2; ++j)
#pragma unroll
      for (int r = 0; r < 16; ++r) cA[i][j][r] = 0.f;

  for (int kt = 0; kt < 8; ++kt) {
#pragma unroll
    for (int i = 0; i < 4; ++i) {
      int idx = tid + i * 256;
      int row = idx >> 3, kc = (idx & 7) * 8;
      int k = kt * 64 + kc;
      {  // A = proj weights (fp32 if F else bf16)
        if constexpr (F) {
          float f[8]; load8<true>(A, (size_t)(m0 + row) * 512 + k, f);
          u32 w0 = (u32)f2bf(f[0]) | ((u32)f2bf(f[1]) << 16);
          u32 w1 = (u32)f2bf(f[2]) | ((u32)f2bf(f[3]) << 16);
          u32 w2 = (u32)f2bf(f[4]) | ((u32)f2bf(f[5]) << 16);
          u32 w3 = (u32)f2bf(f[6]) | ((u32)f2bf(f[7]) << 16);
          *(uint4*)&At[row][kc] = make_uint4(w0, w1, w2, w3);
        } else {
          *(uint4*)&At[row][kc] =
              *(const uint4*)((const u16*)A + (size_t)(m0 + row) * 512 + k);
        }
      }
      *(uint4*)&Bt[row][kc] =
          *(const uint4*)(B + bBase + (size_t)(n0 + row) * 512 + k);
    }
    __syncthreads();
#pragma unroll
    for (int k16 = 0; k16 < 4; ++k16) {
      const int ko = k16 * 16 + hi * 8;
      bf16x8 a0 = *(const bf16x8*)&At[wm * 64 + lo][ko];
      bf16x8 a1 = *(const bf16x8*)&At[wm * 64 + 32 + lo][ko];
      bf16x8 b0 = *(const bf16x8*)&Bt[wn * 64 + lo][ko];
      bf16x8 b1 = *(const bf16x8*)&Bt[wn * 64 + 32 + lo][ko];
      cA[0][0] = MFMA32(a0, b0, cA[0][0]);
      cA[0][1] = MFMA32(a0, b1, cA[0][1]);
      cA[1][0] = MFMA32(a1, b0, cA[1][0]);
      cA[1][1] = MFMA32(a1, b1, cA[1][1]);
    }
    __syncthreads();
  }

#pragma unroll
  for (int mt = 0; mt < 2; ++mt)
#pragma unroll
    for (int nt = 0; nt < 2; ++nt) {
#pragma unroll
      for (int r = 0; r < 16; ++r) {
        int m = m0 + wm * 64 + mt * 32 + (r & 3) + 8 * (r >> 2) + 4 * hi;
        int n = n0 + wn * 64 + nt * 32 + lo;
        float v = cA[mt][nt][r];
        v += load1<F>(bias, m);
        v += load1<F>(resid, bBase + (size_t)m * 1024 + n);
        size_t off = bBase + (size_t)m * 1024 + n;
        if constexpr (F) ((float*)outp)[off] = v;
        else             ((u16*)outp)[off] = f2bf(v);
      }
    }
}

__global__ void __launch_bounds__(256, 4)
proj_rt(const void* __restrict__ projw, const u16* __restrict__ aout,
        const void* __restrict__ projb, const void* __restrict__ x,
        void* __restrict__ outp, const int* __restrict__ flag) {
  __shared__ __align__(16) u16 At[128][72];
  __shared__ __align__(16) u16 Bt[128][72];
  const int n0 = blockIdx.x * 128, m0 = blockIdx.y * 128, b = blockIdx.z;
  if (flag[0] != 0) proj_body<true >(projw, aout, projb, x, outp, n0, m0, b, threadIdx.x, At, Bt);
  else              proj_body<false>(projw, aout, projb, x, outp, n0, m0, b, threadIdx.x, At, Bt);
}

// ---------- K3: MFMA flash attention v2 (proven config, FROZEN) -------------
// qkT[b][s][o] (o<512: Q pre-scaled by QSC, 512..1024: K), V[b][c][s].
// aout[b][s][c] (=xT buffer). Grid (bh, qtile).
__global__ void __launch_bounds__(256, 2) attn4(const u16* __restrict__ qkT,
                                                const u16* __restrict__ V,
                                                u16* __restrict__ aout) {
  const int bh = blockIdx.x;
  const int q0 = blockIdx.y * 128;
  const int b = bh >> 2, h = bh & 3;
  const u16* qt = qkT + (size_t)b * 1048576;
  const u16* vb = V + (size_t)b * 524288 + (size_t)(h * 128) * 1024;
  // buf i at smem[i*16384]: K [64][128] | V (+8192) [128][64]
  __shared__ __align__(16) u16 smem[32768];
  const int tid = threadIdx.x;
  const int w = tid >> 6, lane = tid & 63;
  const int lo = lane & 31, hi = lane >> 5;

  // stage Q -> buf0
#pragma unroll
  for (int c = 0; c < 8; ++c) {
    int grp = w * 8 + c;
    int row = grp * 4 + (lane >> 4);
    int lc  = (lane & 15) ^ (row & 7);
    gl2lds16(qt + (size_t)(q0 + row) * 1024 + h * 128 + lc * 8, &smem[grp * 512]);
  }
  // stage K/V (kt=0) -> buf1
#pragma unroll
  for (int c = 0; c < 4; ++c) {
    int grp = w * 4 + c;
    { int row = grp * 4 + (lane >> 4);
      int lc  = (lane & 15) ^ (row & 7);
      gl2lds16(qt + (size_t)row * 1024 + 512 + h * 128 + lc * 8,
               &smem[16384 + grp * 512]); }
    { int row = grp * 8 + (lane >> 3);
      int lc  = (lane & 7) ^ (row & 7);
      gl2lds16(vb + (size_t)row * 1024 + lc * 8,
               &smem[16384 + 8192 + grp * 512]); }
  }
  __syncthreads();
  bf16x8 qf[8];
  {
    const int row = 32 * w + lo;
#pragma unroll
    for (int k16 = 0; k16 < 8; ++k16) {
      int lc = k16 * 2 + hi;
      qf[k16] = *(const bf16x8*)&smem[row * 128 + ((lc ^ (row & 7)) << 3)];
    }
  }
  __syncthreads();   // Q fragment reads complete before kt=1 stage hits buf0

  f32x16 o[4];
  float lp = 0.f;
#pragma unroll
  for (int dt = 0; dt < 4; ++dt)
#pragma unroll
    for (int r = 0; r < 16; ++r) o[dt][r] = 0.f;

  for (int kt = 0; kt < 16; ++kt) {
    const u16* rb = &smem[((kt & 1) ^ 1) << 14];
    u16* wbuf = &smem[(kt & 1) << 14];

    // stage kt+1 into the other buffer; waited only at this iteration's
    // trailing barrier (vmcnt drain overlaps all compute below)
    if (kt < 15) {
      const int k0n = (kt + 1) * 64;
#pragma unroll
      for (int c = 0; c < 4; ++c) {
        int grp = w * 4 + c;
        { int row = grp * 4 + (lane >> 4);
          int lc  = (lane & 15) ^ (row & 7);
          gl2lds16(qt + (size_t)(k0n + row) * 1024 + 512 + h * 128 + lc * 8,
                   wbuf + grp * 512); }
        { int row = grp * 8 + (lane >> 3);
          int lc  = (lane & 7) ^ (row & 7);
          gl2lds16(vb + (size_t)row * 1024 + k0n + lc * 8,
                   wbuf + 8192 + grp * 512); }
      }
    }

    // S^T = K Q (A = K rows = keys, B = Q cols = q):
    // lane (lo,hi): s0[r] = S[key=(r&3)+8(r>>2)+4hi][q=lo], s1: keys +32
    f32x16 s0, s1;
#pragma unroll
    for (int r = 0; r < 16; ++r) { s0[r] = 0.f; s1[r] = 0.f; }
#pragma unroll
    for (int k16 = 0; k16 < 8; ++k16) {
      const int lc = k16 * 2 + hi;
      const int r0 = lo, r1 = lo + 32;
      bf16x8 kf0 = *(const bf16x8*)&rb[r0 * 128 + ((lc ^ (r0 & 7)) << 3)];
      bf16x8 kf1 = *(const bf16x8*)&rb[r1 * 128 + ((lc ^ (r1 & 7)) << 3)];
      s0 = MFMA32(kf0, qf[k16], s0);
      s1 = MFMA32(kf1, qf[k16], s1);
    }

    // P = exp2(S) in-register; per-lane partial row-sum (q = lo)
#pragma unroll
    for (int r = 0; r < 16; ++r) {
      s0[r] = exp2f(s0[r]);
      s1[r] = exp2f(s1[r]);
      lp += s0[r] + s1[r];
    }

    // Pack P into PV A-frags: pa[t] = P[q=lo][16t + 8*hi .. +7].
    bf16x8 pa[4];
#define MKPA(ps, rb0, dst) do {                                               \
      u32 qa0, qa1, qb0, qb1;                                                 \
      asm("v_cvt_pk_bf16_f32 %0, %1, %2" : "=v"(qa0)                          \
          : "v"((ps)[(rb0) + 0]), "v"((ps)[(rb0) + 1]));                      \
      asm("v_cvt_pk_bf16_f32 %0, %1, %2" : "=v"(qa1)                          \
          : "v"((ps)[(rb0) + 2]), "v"((ps)[(rb0) + 3]));                      \
      asm("v_cvt_pk_bf16_f32 %0, %1, %2" : "=v"(qb0)                          \
          : "v"((ps)[(rb0) + 4]), "v"((ps)[(rb0) + 5]));                      \
      asm("v_cvt_pk_bf16_f32 %0, %1, %2" : "=v"(qb1)                          \
          : "v"((ps)[(rb0) + 6]), "v"((ps)[(rb0) + 7]));                      \
      u32x2 r0 = __builtin_amdgcn_permlane32_swap(qa0, qb0, false, false);    \
      u32x2 r1 = __builtin_amdgcn_permlane32_swap(qa1, qb1, false, false);    \
      union { u32 u[4]; bf16x8 v8; } pk_;                                     \
      pk_.u[0] = r0[0]; pk_.u[1] = r1[0]; pk_.u[2] = r0[1]; pk_.u[3] = r1[1]; \
      dst = pk_.v8;                                                           \
    } while (0)
    MKPA(s0, 0, pa[0]);
    MKPA(s0, 8, pa[1]);
    MKPA(s1, 0, pa[2]);
    MKPA(s1, 8, pa[3]);
#undef MKPA

    // O += P V
#pragma unroll
    for (int t = 0; t < 4; ++t) {
      const int lc = t * 2 + hi;
#pragma unroll
      for (int dt = 0; dt < 4; ++dt) {
        const int row = dt * 32 + lo;
        bf16x8 bv = *(const bf16x8*)&rb[8192 + row * 64 + ((lc ^ (row & 7)) << 3)];
        o[dt] = MFMA32(pa[t], bv, o[dt]);
      }
    }
    __syncthreads();  // reads of rb done by all waves + stage into wbuf landed
  }

  // full row-sum across the hi pair; linv lives at lane lo = q-row
  float linv = 1.f / (lp + __shfl_xor(lp, 32));
#pragma unroll
  for (int r = 0; r < 16; ++r) {
    int pat = (r & 3) + 8 * (r >> 2) + 4 * hi;
    float lr = __shfl(linv, pat);   // broadcast from lane pat (q = pat)
    int q = q0 + 32 * w + pat;
    size_t base = (size_t)(b * 1024 + q) * 512 + h * 128;
    aout[base +  0 + lo] = f2bf(o[0][r] * lr);
    aout[base + 32 + lo] = f2bf(o[1][r] * lr);
    aout[base + 64 + lo] = f2bf(o[2][r] * lr);
    aout[base + 96 + lo] = f2bf(o[3][r] * lr);
  }
}

// ============================================================================
// ====================== FALLBACK PATH (round-4, proven) =====================
// ============================================================================

template <bool F>
__global__ void __launch_bounds__(256) gn_stats(const void* __restrict__ x,
                                                const void* __restrict__ gamma,
                                                const void* __restrict__ beta,
                                                float* __restrict__ sc,
                                                float* __restrict__ bs,
                                                const int* __restrict__ flag) {
  if ((flag[0] != 0) != F) return;
  const int g = blockIdx.x, b = blockIdx.y;
  const int tid = threadIdx.x;
  const size_t base = (size_t)(b * 512 + g * 64) * 1024;
  float sum = 0.f, sq = 0.f;
  for (int i = tid; i < 8192; i += 256) {
    float f[8]; load8<F>(x, base + (size_t)i * 8, f);
#pragma unroll
    for (int m = 0; m < 8; ++m) { sum += f[m]; sq += f[m] * f[m]; }
  }
  __shared__ float ssum[256], ssq[256];
  ssum[tid] = sum; ssq[tid] = sq; __syncthreads();
  for (int off = 128; off > 0; off >>= 1) {
    if (tid < off) { ssum[tid] += ssum[tid + off]; ssq[tid] += ssq[tid + off]; }
    __syncthreads();
  }
  if (tid < 64) {
    float mu  = ssum[0] * (1.f / 65536.f);
    float var = ssq[0] * (1.f / 65536.f) - mu * mu;
    int c = g * 64 + tid;
    float s = load1<F>(gamma, c) * rsqrtf(var + 1e-5f);
    sc[b * 512 + c] = s;
    bs[b * 512 + c] = load1<F>(beta, c) - mu * s;
  }
}

template <bool F, bool BEXT, bool FOUT>
__global__ void __launch_bounds__(256) gemm64(const void* __restrict__ A,
                                              const void* __restrict__ B,
                                              const float* __restrict__ sc,
                                              const float* __restrict__ bs,
                                              const void* __restrict__ bias,
                                              const void* __restrict__ resid,
                                              void* __restrict__ outp,
                                              int mrows, int donorm, int bstride,
                                              const int* __restrict__ flag) {
  if ((flag[0] != 0) != F) return;
  const int s0 = blockIdx.x * 64;
  const int o0 = blockIdx.y * 64;
  const int b  = blockIdx.z;
  __shared__ __align__(16) float At[64][36];
  __shared__ __align__(16) float Bt[64][36];
  const int tid = threadIdx.x;
  const int ty = tid >> 4, tx = tid & 15;
  const int i0 = ty * 4, j0 = tx * 4;
  const int arow = tid >> 2, akc = (tid & 3) * 8;
  const int brow = tid >> 3, bnc = (tid & 7) * 8;
  float acc[4][4] = {};

  for (int kt = 0; kt < 512; kt += 32) {
    float af[8];
    load8<F>(A, (size_t)(o0 + arow) * 512 + akc + kt, af);
    *(float4*)&At[arow][akc]     = make_float4(af[0], af[1], af[2], af[3]);
    *(float4*)&At[arow][akc + 4] = make_float4(af[4], af[5], af[6], af[7]);
    const int c = kt + brow;
    float bf[8];
    load8<(BEXT && F)>(B, (size_t)(b * bstride + c) * 1024 + s0 + bnc, bf);
    float smul = 1.f, badd = 0.f;
    if (donorm) { smul = sc[b * 512 + c]; badd = bs[b * 512 + c]; }
#pragma unroll
    for (int m = 0; m < 8; ++m) Bt[bnc + m][brow] = bf[m] * smul + badd;
    __syncthreads();
#pragma unroll
    for (int kq = 0; kq < 8; ++kq) {
      float4 a0 = *(const float4*)&At[i0 + 0][kq * 4];
      float4 a1 = *(const float4*)&At[i0 + 1][kq * 4];
      float4 a2 = *(const float4*)&At[i0 + 2][kq * 4];
      float4 a3 = *(const float4*)&At[i0 + 3][kq * 4];
      float4 c0 = *(const float4*)&Bt[j0 + 0][kq * 4];
      float4 c1 = *(const float4*)&Bt[j0 + 1][kq * 4];
      float4 c2 = *(const float4*)&Bt[j0 + 2][kq * 4];
      float4 c3 = *(const float4*)&Bt[j0 + 3][kq * 4];
#define DOT4(ii, jj, AV, CV) acc[ii][jj] += AV.x * CV.x + AV.y * CV.y + AV.z * CV.z + AV.w * CV.w;
      DOT4(0,0,a0,c0) DOT4(0,1,a0,c1) DOT4(0,2,a0,c2) DOT4(0,3,a0,c3)
      DOT4(1,0,a1,c0) DOT4(1,1,a1,c1) DOT4(1,2,a1,c2) DOT4(1,3,a1,c3)
      DOT4(2,0,a2,c0) DOT4(2,1,a2,c1) DOT4(2,2,a2,c2) DOT4(2,3,a2,c3)
      DOT4(3,0,a3,c0) DOT4(3,1,a3,c1) DOT4(3,2,a3,c2) DOT4(3,3,a3,c3)
#undef DOT4
    }
    __syncthreads();
  }
#pragma unroll
  for (int ii = 0; ii < 4; ++ii) {
    const int o = o0 + i0 + ii;
    const float bb = load1<F>(bias, o);
    float v[4];
#pragma unroll
    for (int jj = 0; jj < 4; ++jj) v[jj] = acc[ii][jj] + bb;
    if (resid) {
      float xf[4];
      load4<F>(resid, (size_t)(b * 512 + o) * 1024 + s0 + j0, xf);
#pragma unroll
      for (int jj = 0; jj < 4; ++jj) v[jj] += xf[jj];
    }
    const size_t ooff = (size_t)(b * mrows + o) * 1024 + s0 + j0;
    if constexpr (FOUT) {
      *(float4*)((float*)outp + ooff) = make_float4(v[0], v[1], v[2], v[3]);
    } else {
      uint2 pk;
      pk.x = (u32)f2bf(v[0]) | ((u32)f2bf(v[1]) << 16);
      pk.y = (u32)f2bf(v[2]) | ((u32)f2bf(v[3]) << 16);
      *(uint2*)((u16*)outp + ooff) = pk;
    }
  }
}

__global__ void __launch_bounds__(256, 2) attn_old(u16* __restrict__ qkv) {
  const int q0 = blockIdx.x * 128;
  const int bh = blockIdx.y;
  const int b = bh >> 2, h = bh & 3;
  u16* qp = qkv + (size_t)(b * 1536 + h * 128) * 1024;
  const u16* kp = qp + (size_t)512 * 1024;
  const u16* vp = qp + (size_t)1024 * 1024;
  __shared__ __align__(16) u16 Qt[128][136];
  __shared__ __align__(16) u16 Kt[32][136];
  __shared__ __align__(16) u16 Vt[128][40];
  __shared__ __align__(16) u16 Pt[128][40];
  const int tid = threadIdx.x;
  const int w = tid >> 6, lane = tid & 63;
  const int lo = lane & 31, hi = lane >> 5;

  for (int idx = tid; idx < 2048; idx += 256) {
    int d = idx >> 4, s8 = (idx & 15) * 8;
    uint4 qv = *(const uint4*)(qp + (size_t)d * 1024 + q0 + s8);
    const u16* qs = (const u16*)&qv;
#pragma unroll
    for (int m = 0; m < 8; ++m) Qt[s8 + m][d] = qs[m];
  }
  __syncthreads();
  bf16x8 qf[8];
#pragma unroll
  for (int kq = 0; kq < 8; ++kq)
    qf[kq] = *(const bf16x8*)&Qt[32 * w + lo][kq * 16 + hi * 8];

  f32x16 o0, o1, o2, o3;
  float lp[16];
#pragma unroll
  for (int r = 0; r < 16; ++r) { o0[r] = 0.f; o1[r] = 0.f; o2[r] = 0.f; o3[r] = 0.f; lp[r] = 0.f; }

  for (int kt = 0; kt < 32; ++kt) {
    const int k0 = kt * 32;
    __syncthreads();
    for (int idx = tid; idx < 512; idx += 256) {
      int d = idx >> 2, s8 = (idx & 3) * 8;
      uint4 kv = *(const uint4*)(kp + (size_t)d * 1024 + k0 + s8);
      const u16* ks = (const u16*)&kv;
#pragma unroll
      for (int m = 0; m < 8; ++m) Kt[s8 + m][d] = ks[m];
      *(uint4*)&Vt[d][s8] = *(const uint4*)(vp + (size_t)d * 1024 + k0 + s8);
    }
    __syncthreads();
    f32x16 acc;
#pragma unroll
    for (int r = 0; r < 16; ++r) acc[r] = 0.f;
#pragma unroll
    for (int kq = 0; kq < 8; ++kq) {
      bf16x8 bq = *(const bf16x8*)&Kt[lo][kq * 16 + hi * 8];
      acc = MFMA32(qf[kq], bq, acc);
    }
#pragma unroll
    for (int r = 0; r < 16; ++r) {
      float pe = __expf(acc[r] * SM_SCALE);
      lp[r] += pe;
      int row = (r & 3) + 8 * (r >> 2) + 4 * hi;
      Pt[32 * w + row][lo] = f2bf(pe);
    }
    __syncthreads();
#pragma unroll
    for (int kq2 = 0; kq2 < 2; ++kq2) {
      bf16x8 a2 = *(const bf16x8*)&Pt[32 * w + lo][kq2 * 16 + hi * 8];
      bf16x8 b0 = *(const bf16x8*)&Vt[ 0 + lo][kq2 * 16 + hi * 8];
      bf16x8 b1 = *(const bf16x8*)&Vt[32 + lo][kq2 * 16 + hi * 8];
      bf16x8 b2 = *(const bf16x8*)&Vt[64 + lo][kq2 * 16 + hi * 8];
      bf16x8 b3 = *(const bf16x8*)&Vt[96 + lo][kq2 * 16 + hi * 8];
      o0 = MFMA32(a2, b0, o0);
      o1 = MFMA32(a2, b1, o1);
      o2 = MFMA32(a2, b2, o2);
      o3 = MFMA32(a2, b3, o3);
    }
  }
#pragma unroll
  for (int r = 0; r < 16; ++r) {
    float su = lp[r];
    su += __shfl_xor(su, 1);  su += __shfl_xor(su, 2);
    su += __shfl_xor(su, 4);  su += __shfl_xor(su, 8);
    su += __shfl_xor(su, 16);
    float linv = 1.f / su;
    int row = (r & 3) + 8 * (r >> 2) + 4 * hi;
    int q = q0 + 32 * w + row;
    size_t base = (size_t)(b * 1536 + h * 128) * 1024 + q;
    qkv[base + (size_t)( 0 + lo) * 1024] = f2bf(o0[r] * linv);
    qkv[base + (size_t)(32 + lo) * 1024] = f2bf(o1[r] * linv);
    qkv[base + (size_t)(64 + lo) * 1024] = f2bf(o2[r] * linv);
    qkv[base + (size_t)(96 + lo) * 1024] = f2bf(o3[r] * linv);
  }
}

// ---------- launch ----------
extern "C" void kernel_launch(void* const* d_in, const int* in_sizes, int n_in,
                              void* d_out, int out_size, void* d_ws, size_t ws_size,
                              hipStream_t stream) {
  const void* x     = d_in[0];
  const void* gamma = d_in[1];
  const void* beta  = d_in[2];
  const void* qkvw  = d_in[3];
  const void* qkvb  = d_in[4];
  const void* projw = d_in[5];
  const void* projb = d_in[6];

  char* ws = (char*)d_ws;
  const size_t MB = 1024 * 1024;
  const size_t FAST_NEED = 64 * MB + 64;
  const size_t OLD_NEED  = 48 * MB + 256 + 2 * 16 * 512 * 4;

  if (ws_size >= FAST_NEED) {
    u16* xT   = (u16*)ws;                 // [16][1024][512] normalized; reused as aout
    u16* qkT  = (u16*)(ws + 16 * MB);     // [16][1024][1024] (Q'|K per token row)
    u16* Vbuf = (u16*)(ws + 48 * MB);     // [16][512][1024]
    int* flag = (int*)(ws + 64 * MB);
    u16* wbf  = (u16*)d_out;              // bf16 qkv weights+bias (1.54 MB);
                                          // dead region until proj overwrites
    float* part = (float*)((char*)d_out + 2 * MB);  // [16][8][2][2] gn partials
                                          // (dead d_out region past wbf;
                                          //  consumed before proj writes)

    detect_dtype<<<1, 64, 0, stream>>>(x, flag);
    wconv_rt<<<385, 256, 0, stream>>>(qkvw, qkvb, wbf, flag);
    // GroupNorm: 256-block stats + 256-block apply (was one 128-block kernel
    // = half the CUs idle on a memory-bound pass)
    gn_stats2<<<dim3(8, 16, 2), 256, 0, stream>>>(x, part, flag);
    gn_apply<<<dim3(16, 16), 256, 0, stream>>>(x, gamma, beta, part, xT, flag);

    // merged qk + v GEMM (single-buffer, natural block map — r3 config)
    gemm_qkv<<<dim3(8, 12, 16), 256, 0, stream>>>(xT, wbf, qkT, Vbuf);

    attn4<<<dim3(64, 8), 256, 0, stream>>>(qkT, Vbuf, xT);  // aout overwrites xT

    // proj: D[o][s] = projW[o][:] . aout[s][:] + proj_b[o] + x
    proj_rt<<<dim3(8, 4, 16), 256, 0, stream>>>(projw, xT, projb, x, d_out, flag);
    return;
  }

  if (ws_size < OLD_NEED) {
    signal_ws<<<(out_size + 255) / 256, 256, 0, stream>>>((u16*)d_out, out_size);
    return;
  }

  // ---- round-4 fallback ----
  const size_t QKV_BYTES = (size_t)16 * 1536 * 1024 * 2;
  u16* qkv  = (u16*)ws;
  int* flag = (int*)(ws + QKV_BYTES);
  float* sc = (float*)(ws + QKV_BYTES + 256);
  float* bs = sc + 16 * 512;

  detect_dtype<<<1, 64, 0, stream>>>(x, flag);
  gn_stats<false><<<dim3(8, 16), 256, 0, stream>>>(x, gamma, beta, sc, bs, flag);
  gn_stats<true ><<<dim3(8, 16), 256, 0, stream>>>(x, gamma, beta, sc, bs, flag);
  gemm64<false, true, false><<<dim3(16, 24, 16), 256, 0, stream>>>(
      qkvw, x, sc, bs, qkvb, nullptr, qkv, 1536, 1, 512, flag);
  gemm64<true, true, false><<<dim3(16, 24, 16), 256, 0, stream>>>(
      qkvw, x, sc, bs, qkvb, nullptr, qkv, 1536, 1, 512, flag);
  attn_old<<<dim3(8, 64), 256, 0, stream>>>(qkv);
  gemm64<false, false, false><<<dim3(16, 8, 16), 256, 0, stream>>>(
      projw, qkv, sc, bs, projb, x, d_out, 512, 0, 1536, flag);
  gemm64<true, false, true><<<dim3(16, 8, 16), 256, 0, stream>>>(
      projw, qkv, sc, bs, projb, x, d_out, 512, 0, 1536, flag);
}

// Round 9
// 225.657 us; speedup vs baseline: 1.1638x; 1.0536x over previous
//
#include <hip/hip_runtime.h>

typedef unsigned short u16;
typedef unsigned int   u32;

typedef __attribute__((ext_vector_type(8)))  short bf16x8;
typedef __attribute__((ext_vector_type(16))) float f32x16;
typedef __attribute__((ext_vector_type(2)))  unsigned int u32x2;
#define MFMA32(a, b, c) __builtin_amdgcn_mfma_f32_32x32x16_bf16(a, b, c, 0, 0, 0)

// ---------- bf16 helpers ----------
__device__ __forceinline__ float bf2f(u16 h) { return __uint_as_float(((u32)h) << 16); }
__device__ __forceinline__ u16 f2bf(float f) {
  u32 u = __float_as_uint(f);
  u += 0x7fffu + ((u >> 16) & 1u);   // RNE
  return (u16)(u >> 16);
}
__device__ __forceinline__ void unpack8(uint4 u, float* f) {
  f[0] = __uint_as_float(u.x << 16); f[1] = __uint_as_float(u.x & 0xffff0000u);
  f[2] = __uint_as_float(u.y << 16); f[3] = __uint_as_float(u.y & 0xffff0000u);
  f[4] = __uint_as_float(u.z << 16); f[5] = __uint_as_float(u.z & 0xffff0000u);
  f[6] = __uint_as_float(u.w << 16); f[7] = __uint_as_float(u.w & 0xffff0000u);
}
__device__ __forceinline__ void unpack4(uint2 u, float* f) {
  f[0] = __uint_as_float(u.x << 16); f[1] = __uint_as_float(u.x & 0xffff0000u);
  f[2] = __uint_as_float(u.y << 16); f[3] = __uint_as_float(u.y & 0xffff0000u);
}

// ---------- dtype-polymorphic loads (template = pointer holds fp32) ----------
template <bool F>
__device__ __forceinline__ void load8(const void* p, size_t idx, float* f) {
  if constexpr (F) {
    const float4* q = (const float4*)((const float*)p + idx);
    float4 a = q[0], b = q[1];
    f[0] = a.x; f[1] = a.y; f[2] = a.z; f[3] = a.w;
    f[4] = b.x; f[5] = b.y; f[6] = b.z; f[7] = b.w;
  } else {
    unpack8(*(const uint4*)((const u16*)p + idx), f);
  }
}
template <bool F>
__device__ __forceinline__ void load4(const void* p, size_t idx, float* f) {
  if constexpr (F) {
    float4 a = *(const float4*)((const float*)p + idx);
    f[0] = a.x; f[1] = a.y; f[2] = a.z; f[3] = a.w;
  } else {
    unpack4(*(const uint2*)((const u16*)p + idx), f);
  }
}
template <bool F>
__device__ __forceinline__ float load1(const void* p, size_t idx) {
  if constexpr (F) return ((const float*)p)[idx];
  else return bf2f(((const u16*)p)[idx]);
}

// ---------- async global -> LDS, 16B per lane ----------
__device__ __forceinline__ void gl2lds16(const void* g, void* l) {
  __builtin_amdgcn_global_load_lds(
      (const __attribute__((address_space(1))) void*)g,
      (__attribute__((address_space(3))) void*)l, 16, 0, 0);
}

// ---------- per-block dtype detect (inline; replaces the detect launch) -----
// Same decision rule as the old detect_dtype: sample x[0..255] as u32, count
// fp32-plausible exponents; <192 sane => fp32. All blocks are 256 threads.
__device__ __forceinline__ bool blk_is_f32(const void* x, int tid, int* sh) {
  const u32* p = (const u32*)x;
  u32 e = (p[tid] >> 7) & 0xFFu;
  sh[tid] = (e >= 100u && e <= 150u) ? 1 : 0;
  __syncthreads();
  for (int off = 128; off > 0; off >>= 1) {
    if (tid < off) sh[tid] += sh[tid + off];
    __syncthreads();
  }
  bool r = sh[0] < 192;
  __syncthreads();
  return r;
}

// ---------- dtype detect kernel (FALLBACK path only) ----------
__global__ void detect_dtype(const void* __restrict__ x, int* __restrict__ flag) {
  if (threadIdx.x == 0 && blockIdx.x == 0) {
    const u32* p = (const u32*)x;
    int sane = 0;
    for (int i = 0; i < 256; ++i) {
      u32 e = (p[i] >> 7) & 0xFFu;
      sane += (e >= 100u && e <= 150u) ? 1 : 0;
    }
    *flag = (sane < 192) ? 1 : 0;
  }
}

// ---------- diagnostic ----------
__global__ void signal_ws(u16* __restrict__ out, int n) {
  int i = blockIdx.x * 256 + threadIdx.x;
  if (i < n) out[i] = 0x42C8;  // bf16 100.0
}

#define SM_SCALE 0.08838834764831843f
// SM_SCALE * log2(e): Q pre-scale so softmax is a bare exp2
#define QSC 0.12751743f

// ============================================================================
// =========================== FAST PATH (needs 64 MiB ws) ====================
// ============================================================================

// ---------- K0: merged {wconv | gn_stats} (r8: was 3 launches incl detect) --
// Grid 641 blocks: bx<256 = stats role (bx = half*128 + b*8 + g, each block
// reduces 32ch x 1024pos -> part[(b*8+g)*4 + half*2]); bx>=256 = wconv role
// (qkv weights+bias fp32->bf16, x8 vectorized). Flag computed per-block.
__global__ void __launch_bounds__(256) prep_rt(const void* __restrict__ x,
                                               const void* __restrict__ qkvw,
                                               const void* __restrict__ qkvb,
                                               u16* __restrict__ wdst,
                                               float* __restrict__ part) {
  __shared__ float ssum[256], ssq[256];
  __shared__ int sfl[256];
  const int tid = threadIdx.x;
  const bool F = blk_is_f32(x, tid, sfl);
  const int bx = blockIdx.x;

  if (bx < 256) {  // ---- stats role ----
    const int g = bx & 7, b = (bx >> 3) & 15, half = bx >> 7;
    const size_t base = (size_t)(b * 512 + g * 64 + half * 32) * 1024;
    float sum = 0.f, sq = 0.f;
    if (F) {
      for (int i = tid; i < 4096; i += 256) {
        float f[8]; load8<true>(x, base + (size_t)i * 8, f);
#pragma unroll
        for (int m = 0; m < 8; ++m) { sum += f[m]; sq += f[m] * f[m]; }
      }
    } else {
      for (int i = tid; i < 4096; i += 256) {
        float f[8]; load8<false>(x, base + (size_t)i * 8, f);
#pragma unroll
        for (int m = 0; m < 8; ++m) { sum += f[m]; sq += f[m] * f[m]; }
      }
    }
    ssum[tid] = sum; ssq[tid] = sq; __syncthreads();
    for (int off = 128; off > 0; off >>= 1) {
      if (tid < off) { ssum[tid] += ssum[tid + off]; ssq[tid] += ssq[tid + off]; }
      __syncthreads();
    }
    if (tid == 0) {
      part[(b * 8 + g) * 4 + half * 2 + 0] = ssum[0];
      part[(b * 8 + g) * 4 + half * 2 + 1] = ssq[0];
    }
  } else {  // ---- wconv role ----
    int i = ((bx - 256) * 256 + tid) * 8;
    if (i >= 787968) return;
    if (!F) {
      uint4 v = (i < 786432) ? *(const uint4*)((const u16*)qkvw + i)
                             : *(const uint4*)((const u16*)qkvb + (i - 786432));
      *(uint4*)(wdst + i) = v;
    } else {
      const float* src = (i < 786432) ? ((const float*)qkvw + i)
                                      : ((const float*)qkvb + (i - 786432));
      float4 a = *(const float4*)src, b4 = *(const float4*)(src + 4);
      u32 w0 = (u32)f2bf(a.x) | ((u32)f2bf(a.y) << 16);
      u32 w1 = (u32)f2bf(a.z) | ((u32)f2bf(a.w) << 16);
      u32 w2 = (u32)f2bf(b4.x) | ((u32)f2bf(b4.y) << 16);
      u32 w3 = (u32)f2bf(b4.z) | ((u32)f2bf(b4.w) << 16);
      *(uint4*)(wdst + i) = make_uint4(w0, w1, w2, w3);
    }
  }
}

// ---------- K1b: GroupNorm apply + transpose -> xT[b][s][c] -----------------
// r9: grid (16 chunks, 16 batches, 4 z) = 1024 blocks = 4/CU (was 256 = 1/CU
// — a memory-bound transpose at 12.5% occupancy). Each block: 64 tokens x
// 128 channels (2 group-blocks of z), dbuf'd Tf transpose (proven r4-r8).
template <bool F>
__device__ __forceinline__ void gn_apply_body(
    const void* __restrict__ x, const void* __restrict__ gamma,
    const void* __restrict__ beta, const float* __restrict__ part,
    u16* __restrict__ xT, int chunk, int b, int z, int tid,
    float* scb, float* bsb, float (*Tf)[64][65]) {
  const int s0 = chunk * 64;
  if (tid < 128) {
    int gg = z * 2 + (tid >> 6);
    const float* p = part + (b * 8 + gg) * 4;
    float sum = p[0] + p[2], sq = p[1] + p[3];
    float mu  = sum * (1.f / 65536.f);
    float var = sq * (1.f / 65536.f) - mu * mu;
    int c = z * 128 + tid;
    float s = load1<F>(gamma, c) * rsqrtf(var + 1e-5f);
    scb[tid] = s;
    bsb[tid] = load1<F>(beta, c) - mu * s;
  }
  __syncthreads();

  for (int gb = 0; gb < 2; ++gb) {
    const int pb = gb & 1;
#pragma unroll
    for (int half = 0; half < 2; ++half) {
      int idx = tid + half * 256;
      int c_loc = idx >> 3, s8 = (idx & 7) * 8;   // c_loc 0..63 within group
      int c = (z * 2 + gb) * 64 + c_loc;
      float f[8];
      load8<F>(x, (size_t)(b * 512 + c) * 1024 + s0 + s8, f);
      float sm = scb[gb * 64 + c_loc], ba = bsb[gb * 64 + c_loc];
#pragma unroll
      for (int m = 0; m < 8; ++m) Tf[pb][s8 + m][c_loc] = f[m] * sm + ba;
    }
    __syncthreads();
#pragma unroll
    for (int half = 0; half < 2; ++half) {
      int idx = tid + half * 256;
      int s_loc = idx >> 3, c8 = (idx & 7) * 8;
      u32 pk[4];
#pragma unroll
      for (int m = 0; m < 4; ++m)
        pk[m] = (u32)f2bf(Tf[pb][s_loc][c8 + 2 * m]) |
                ((u32)f2bf(Tf[pb][s_loc][c8 + 2 * m + 1]) << 16);
      *(uint4*)(xT + (size_t)(b * 1024 + s0 + s_loc) * 512 +
                (z * 2 + gb) * 64 + c8) = make_uint4(pk[0], pk[1], pk[2], pk[3]);
    }
    // dbuf: gb0/gb1 use different Tf buffers; no trailing barrier needed.
  }
}

__global__ void __launch_bounds__(256) gn_apply(const void* __restrict__ x,
                                                const void* __restrict__ gamma,
                                                const void* __restrict__ beta,
                                                const float* __restrict__ part,
                                                u16* __restrict__ xT) {
  __shared__ float scb[128], bsb[128];
  __shared__ float Tf[2][64][65];
  __shared__ int sfl[256];
  const int chunk = blockIdx.x, b = blockIdx.y, z = blockIdx.z, tid = threadIdx.x;
  const bool F = blk_is_f32(x, tid, sfl);
  if (F) gn_apply_body<true >(x, gamma, beta, part, xT, chunk, b, z, tid, scb, bsb, Tf);
  else   gn_apply_body<false>(x, gamma, beta, part, xT, chunk, b, z, tid, scb, bsb, Tf);
}

// ---------- K2: merged qk + v MFMA GEMM (r3-proven config, FROZEN) ----------
// A/B HISTORY: natural map ~51.5 us (r3/r7/r8) beats XCD-swizzle 64.1 (r6)
// and dbuf+swizzle 60.9 (r5). FETCH 71.6 MB @2.5 TB/s free-flowing beats
// 22.6 MB @1.2 TB/s serialized — locality tweaks trade parallelism of misses
// for fewer misses and LOSE. Closed.
// Grid (8, 12, 16): y<8 = qk role (D[s][o], Q cols pre-scaled), y>=8 = v
// role (D[c][s]). Block-uniform selects. LDS unpadded flat [128][64] u16,
// XOR chunk swizzle realized on the global SOURCE address.
__global__ void __launch_bounds__(256, 4)
gemm_qkv(const u16* __restrict__ xT, const u16* __restrict__ wbf,
         u16* __restrict__ qkT, u16* __restrict__ Vbuf) {
  const bool vrole = (blockIdx.y >= 8);
  const int n0 = blockIdx.x * 128;
  const int m0 = (vrole ? (int)blockIdx.y - 8 : (int)blockIdx.y) * 128;
  const int b  = blockIdx.z;
  __shared__ __align__(16) u16 At[8192];   // 128 rows x 64 u16 (128 B)
  __shared__ __align__(16) u16 Bt[8192];
  const int tid = threadIdx.x;
  const int w = tid >> 6, lane = tid & 63;
  const int lo = lane & 31, hi = lane >> 5;
  const int wm = w >> 1, wn = w & 1;
  const u16* bias = wbf + 786432;
  const u16* Ab = vrole ? (wbf + 524288) : (xT + (size_t)b * 524288);
  const u16* Bb = vrole ? (xT + (size_t)b * 524288) : wbf;
  u16* outp = vrole ? (Vbuf + (size_t)b * 524288) : (qkT + (size_t)b * 1048576);
  const int srow = lane >> 3, spc = lane & 7;

  f32x16 cA[2][2];
#pragma unroll
  for (int i = 0; i < 2; ++i)
#pragma unroll
    for (int j = 0; j < 2; ++j)
#pragma unroll
      for (int r = 0; r < 16; ++r) cA[i][j][r] = 0.f;

  for (int kt = 0; kt < 8; ++kt) {
    const int kb = kt * 64;
#pragma unroll
    for (int c = 0; c < 4; ++c) {
      int grp = w * 4 + c;                 // 16 groups of 1 KB
      int row = grp * 8 + srow;            // 0..127
      int lc  = spc ^ (row & 7);
      gl2lds16(Ab + (size_t)(m0 + row) * 512 + kb + lc * 8, &At[grp * 512]);
      gl2lds16(Bb + (size_t)(n0 + row) * 512 + kb + lc * 8, &Bt[grp * 512]);
    }
    __syncthreads();
#pragma unroll
    for (int k16 = 0; k16 < 4; ++k16) {
      const int lc = k16 * 2 + hi;
      const int rA0 = wm * 64 + lo,  rA1 = rA0 + 32;
      const int rB0 = wn * 64 + lo,  rB1 = rB0 + 32;
      bf16x8 a0 = *(const bf16x8*)&At[rA0 * 64 + ((lc ^ (rA0 & 7)) << 3)];
      bf16x8 a1 = *(const bf16x8*)&At[rA1 * 64 + ((lc ^ (rA1 & 7)) << 3)];
      bf16x8 b0 = *(const bf16x8*)&Bt[rB0 * 64 + ((lc ^ (rB0 & 7)) << 3)];
      bf16x8 b1 = *(const bf16x8*)&Bt[rB1 * 64 + ((lc ^ (rB1 & 7)) << 3)];
      cA[0][0] = MFMA32(a0, b0, cA[0][0]);
      cA[0][1] = MFMA32(a0, b1, cA[0][1]);
      cA[1][0] = MFMA32(a1, b0, cA[1][0]);
      cA[1][1] = MFMA32(a1, b1, cA[1][1]);
    }
    __syncthreads();
  }

  float bcol[2] = {0.f, 0.f};
  if (!vrole) {
    bcol[0] = bf2f(bias[n0 + wn * 64 + lo]);
    bcol[1] = bf2f(bias[n0 + wn * 64 + 32 + lo]);
  }
#pragma unroll
  for (int mt = 0; mt < 2; ++mt)
#pragma unroll
    for (int nt = 0; nt < 2; ++nt) {
      const int nbase = n0 + wn * 64 + nt * 32;
#pragma unroll
      for (int r = 0; r < 16; ++r) {
        int m = m0 + wm * 64 + mt * 32 + (r & 3) + 8 * (r >> 2) + 4 * hi;
        int n = nbase + lo;
        float v = cA[mt][nt][r];
        if (!vrole) {
          v += bcol[nt];
          if (nbase < 512) v *= QSC;
        } else {
          v += bf2f(bias[1024 + m]);
        }
        outp[(size_t)m * 1024 + n] = f2bf(v);
      }
    }
}

// ---------- K2b (proj): MFMA GEMM (VGPR staging), inline flag ---------------
// D[o][s] = projW[o].aout[s] + proj_b[o] + x[b][o][s]; out dtype follows input.
template <bool F>
__device__ __forceinline__ void proj_body(const void* __restrict__ A,
                                          const u16* __restrict__ B,
                                          const void* __restrict__ bias,
                                          const void* __restrict__ resid,
                                          void* __restrict__ outp,
                                          int n0, int m0, int b, int tid,
                                          u16 (*At)[72], u16 (*Bt)[72]) {
  const int w = tid >> 6, lane = tid & 63;
  const int lo = lane & 31, hi = lane >> 5;
  const int wm = w >> 1, wn = w & 1;
  const size_t bBase = (size_t)b * 524288;

  f32x16 cA[2][2];
#pragma unroll
  for (int i = 0; i < 2; ++i)
#pragma unroll
    for (int j = 0; j < 2; ++j)
#pragma unroll
      for (int r = 0; r < 16; ++r) cA[i][j][r] = 0.f;

  for (int kt = 0; kt < 8; ++kt) {
#pragma unroll
    for (int i = 0; i < 4; ++i) {
      int idx = tid + i * 256;
      int row = idx >> 3, kc = (idx & 7) * 8;
      int k = kt * 64 + kc;
      {  // A = proj weights (fp32 if F else bf16)
        if constexpr (F) {
          float f[8]; load8<true>(A, (size_t)(m0 + row) * 512 + k, f);
          u32 w0 = (u32)f2bf(f[0]) | ((u32)f2bf(f[1]) << 16);
          u32 w1 = (u32)f2bf(f[2]) | ((u32)f2bf(f[3]) << 16);
          u32 w2 = (u32)f2bf(f[4]) | ((u32)f2bf(f[5]) << 16);
          u32 w3 = (u32)f2bf(f[6]) | ((u32)f2bf(f[7]) << 16);
          *(uint4*)&At[row][kc] = make_uint4(w0, w1, w2, w3);
        } else {
          *(uint4*)&At[row][kc] =
              *(const uint4*)((const u16*)A + (size_t)(m0 + row) * 512 + k);
        }
      }
      *(uint4*)&Bt[row][kc] =
          *(const uint4*)(B + bBase + (size_t)(n0 + row) * 512 + k);
    }
    __syncthreads();
#pragma unroll
    for (int k16 = 0; k16 < 4; ++k16) {
      const int ko = k16 * 16 + hi * 8;
      bf16x8 a0 = *(const bf16x8*)&At[wm * 64 + lo][ko];
      bf16x8 a1 = *(const bf16x8*)&At[wm * 64 + 32 + lo][ko];
      bf16x8 b0 = *(const bf16x8*)&Bt[wn * 64 + lo][ko];
      bf16x8 b1 = *(const bf16x8*)&Bt[wn * 64 + 32 + lo][ko];
      cA[0][0] = MFMA32(a0, b0, cA[0][0]);
      cA[0][1] = MFMA32(a0, b1, cA[0][1]);
      cA[1][0] = MFMA32(a1, b0, cA[1][0]);
      cA[1][1] = MFMA32(a1, b1, cA[1][1]);
    }
    __syncthreads();
  }

#pragma unroll
  for (int mt = 0; mt < 2; ++mt)
#pragma unroll
    for (int nt = 0; nt < 2; ++nt) {
#pragma unroll
      for (int r = 0; r < 16; ++r) {
        int m = m0 + wm * 64 + mt * 32 + (r & 3) + 8 * (r >> 2) + 4 * hi;
        int n = n0 + wn * 64 + nt * 32 + lo;
        float v = cA[mt][nt][r];
        v += load1<F>(bias, m);
        v += load1<F>(resid, bBase + (size_t)m * 1024 + n);
        size_t off = bBase + (size_t)m * 1024 + n;
        if constexpr (F) ((float*)outp)[off] = v;
        else             ((u16*)outp)[off] = f2bf(v);
      }
    }
}

__global__ void __launch_bounds__(256, 4)
proj_rt(const void* __restrict__ projw, const u16* __restrict__ aout,
        const void* __restrict__ projb, const void* __restrict__ x,
        void* __restrict__ outp) {
  __shared__ __align__(16) u16 At[128][72];
  __shared__ __align__(16) u16 Bt[128][72];
  __shared__ int sfl[256];
  const int n0 = blockIdx.x * 128, m0 = blockIdx.y * 128, b = blockIdx.z;
  const bool F = blk_is_f32(x, threadIdx.x, sfl);
  if (F) proj_body<true >(projw, aout, projb, x, outp, n0, m0, b, threadIdx.x, At, Bt);
  else   proj_body<false>(projw, aout, projb, x, outp, n0, m0, b, threadIdx.x, At, Bt);
}

// ---------- K3: MFMA flash attention v2 (proven config, FROZEN) -------------
// qkT[b][s][o] (o<512: Q pre-scaled by QSC, 512..1024: K), V[b][c][s].
// aout[b][s][c] (=xT buffer). Grid (bh, qtile).
__global__ void __launch_bounds__(256, 2) attn4(const u16* __restrict__ qkT,
                                                const u16* __restrict__ V,
                                                u16* __restrict__ aout) {
  const int bh = blockIdx.x;
  const int q0 = blockIdx.y * 128;
  const int b = bh >> 2, h = bh & 3;
  const u16* qt = qkT + (size_t)b * 1048576;
  const u16* vb = V + (size_t)b * 524288 + (size_t)(h * 128) * 1024;
  // buf i at smem[i*16384]: K [64][128] | V (+8192) [128][64]
  __shared__ __align__(16) u16 smem[32768];
  const int tid = threadIdx.x;
  const int w = tid >> 6, lane = tid & 63;
  const int lo = lane & 31, hi = lane >> 5;

  // stage Q -> buf0
#pragma unroll
  for (int c = 0; c < 8; ++c) {
    int grp = w * 8 + c;
    int row = grp * 4 + (lane >> 4);
    int lc  = (lane & 15) ^ (row & 7);
    gl2lds16(qt + (size_t)(q0 + row) * 1024 + h * 128 + lc * 8, &smem[grp * 512]);
  }
  // stage K/V (kt=0) -> buf1
#pragma unroll
  for (int c = 0; c < 4; ++c) {
    int grp = w * 4 + c;
    { int row = grp * 4 + (lane >> 4);
      int lc  = (lane & 15) ^ (row & 7);
      gl2lds16(qt + (size_t)row * 1024 + 512 + h * 128 + lc * 8,
               &smem[16384 + grp * 512]); }
    { int row = grp * 8 + (lane >> 3);
      int lc  = (lane & 7) ^ (row & 7);
      gl2lds16(vb + (size_t)row * 1024 + lc * 8,
               &smem[16384 + 8192 + grp * 512]); }
  }
  __syncthreads();
  bf16x8 qf[8];
  {
    const int row = 32 * w + lo;
#pragma unroll
    for (int k16 = 0; k16 < 8; ++k16) {
      int lc = k16 * 2 + hi;
      qf[k16] = *(const bf16x8*)&smem[row * 128 + ((lc ^ (row & 7)) << 3)];
    }
  }
  __syncthreads();   // Q fragment reads complete before kt=1 stage hits buf0

  f32x16 o[4];
  float lp = 0.f;
#pragma unroll
  for (int dt = 0; dt < 4; ++dt)
#pragma unroll
    for (int r = 0; r < 16; ++r) o[dt][r] = 0.f;

  for (int kt = 0; kt < 16; ++kt) {
    const u16* rb = &smem[((kt & 1) ^ 1) << 14];
    u16* wbuf = &smem[(kt & 1) << 14];

    // stage kt+1 into the other buffer; waited only at this iteration's
    // trailing barrier (vmcnt drain overlaps all compute below)
    if (kt < 15) {
      const int k0n = (kt + 1) * 64;
#pragma unroll
      for (int c = 0; c < 4; ++c) {
        int grp = w * 4 + c;
        { int row = grp * 4 + (lane >> 4);
          int lc  = (lane & 15) ^ (row & 7);
          gl2lds16(qt + (size_t)(k0n + row) * 1024 + 512 + h * 128 + lc * 8,
                   wbuf + grp * 512); }
        { int row = grp * 8 + (lane >> 3);
          int lc  = (lane & 7) ^ (row & 7);
          gl2lds16(vb + (size_t)row * 1024 + k0n + lc * 8,
                   wbuf + 8192 + grp * 512); }
      }
    }

    // S^T = K Q (A = K rows = keys, B = Q cols = q):
    // lane (lo,hi): s0[r] = S[key=(r&3)+8(r>>2)+4hi][q=lo], s1: keys +32
    f32x16 s0, s1;
#pragma unroll
    for (int r = 0; r < 16; ++r) { s0[r] = 0.f; s1[r] = 0.f; }
#pragma unroll
    for (int k16 = 0; k16 < 8; ++k16) {
      const int lc = k16 * 2 + hi;
      const int r0 = lo, r1 = lo + 32;
      bf16x8 kf0 = *(const bf16x8*)&rb[r0 * 128 + ((lc ^ (r0 & 7)) << 3)];
      bf16x8 kf1 = *(const bf16x8*)&rb[r1 * 128 + ((lc ^ (r1 & 7)) << 3)];
      s0 = MFMA32(kf0, qf[k16], s0);
      s1 = MFMA32(kf1, qf[k16], s1);
    }

    // P = exp2(S) in-register; per-lane partial row-sum (q = lo)
#pragma unroll
    for (int r = 0; r < 16; ++r) {
      s0[r] = exp2f(s0[r]);
      s1[r] = exp2f(s1[r]);
      lp += s0[r] + s1[r];
    }

    // Pack P into PV A-frags: pa[t] = P[q=lo][16t + 8*hi .. +7].
    bf16x8 pa[4];
#define MKPA(ps, rb0, dst) do {                                               \
      u32 qa0, qa1, qb0, qb1;                                                 \
      asm("v_cvt_pk_bf16_f32 %0, %1, %2" : "=v"(qa0)                          \
          : "v"((ps)[(rb0) + 0]), "v"((ps)[(rb0) + 1]));                      \
      asm("v_cvt_pk_bf16_f32 %0, %1, %2" : "=v"(qa1)                          \
          : "v"((ps)[(rb0) + 2]), "v"((ps)[(rb0) + 3]));                      \
      asm("v_cvt_pk_bf16_f32 %0, %1, %2" : "=v"(qb0)                          \
          : "v"((ps)[(rb0) + 4]), "v"((ps)[(rb0) + 5]));                      \
      asm("v_cvt_pk_bf16_f32 %0, %1, %2" : "=v"(qb1)                          \
          : "v"((ps)[(rb0) + 6]), "v"((ps)[(rb0) + 7]));                      \
      u32x2 r0 = __builtin_amdgcn_permlane32_swap(qa0, qb0, false, false);    \
      u32x2 r1 = __builtin_amdgcn_permlane32_swap(qa1, qb1, false, false);    \
      union { u32 u[4]; bf16x8 v8; } pk_;                                     \
      pk_.u[0] = r0[0]; pk_.u[1] = r1[0]; pk_.u[2] = r0[1]; pk_.u[3] = r1[1]; \
      dst = pk_.v8;                                                           \
    } while (0)
    MKPA(s0, 0, pa[0]);
    MKPA(s0, 8, pa[1]);
    MKPA(s1, 0, pa[2]);
    MKPA(s1, 8, pa[3]);
#undef MKPA

    // O += P V
#pragma unroll
    for (int t = 0; t < 4; ++t) {
      const int lc = t * 2 + hi;
#pragma unroll
      for (int dt = 0; dt < 4; ++dt) {
        const int row = dt * 32 + lo;
        bf16x8 bv = *(const bf16x8*)&rb[8192 + row * 64 + ((lc ^ (row & 7)) << 3)];
        o[dt] = MFMA32(pa[t], bv, o[dt]);
      }
    }
    __syncthreads();  // reads of rb done by all waves + stage into wbuf landed
  }

  // full row-sum across the hi pair; linv lives at lane lo = q-row
  float linv = 1.f / (lp + __shfl_xor(lp, 32));
#pragma unroll
  for (int r = 0; r < 16; ++r) {
    int pat = (r & 3) + 8 * (r >> 2) + 4 * hi;
    float lr = __shfl(linv, pat);   // broadcast from lane pat (q = pat)
    int q = q0 + 32 * w + pat;
    size_t base = (size_t)(b * 1024 + q) * 512 + h * 128;
    aout[base +  0 + lo] = f2bf(o[0][r] * lr);
    aout[base + 32 + lo] = f2bf(o[1][r] * lr);
    aout[base + 64 + lo] = f2bf(o[2][r] * lr);
    aout[base + 96 + lo] = f2bf(o[3][r] * lr);
  }
}

// ============================================================================
// ====================== FALLBACK PATH (round-4, proven) =====================
// ============================================================================

template <bool F>
__global__ void __launch_bounds__(256) gn_stats(const void* __restrict__ x,
                                                const void* __restrict__ gamma,
                                                const void* __restrict__ beta,
                                                float* __restrict__ sc,
                                                float* __restrict__ bs,
                                                const int* __restrict__ flag) {
  if ((flag[0] != 0) != F) return;
  const int g = blockIdx.x, b = blockIdx.y;
  const int tid = threadIdx.x;
  const size_t base = (size_t)(b * 512 + g * 64) * 1024;
  float sum = 0.f, sq = 0.f;
  for (int i = tid; i < 8192; i += 256) {
    float f[8]; load8<F>(x, base + (size_t)i * 8, f);
#pragma unroll
    for (int m = 0; m < 8; ++m) { sum += f[m]; sq += f[m] * f[m]; }
  }
  __shared__ float ssum[256], ssq[256];
  ssum[tid] = sum; ssq[tid] = sq; __syncthreads();
  for (int off = 128; off > 0; off >>= 1) {
    if (tid < off) { ssum[tid] += ssum[tid + off]; ssq[tid] += ssq[tid + off]; }
    __syncthreads();
  }
  if (tid < 64) {
    float mu  = ssum[0] * (1.f / 65536.f);
    float var = ssq[0] * (1.f / 65536.f) - mu * mu;
    int c = g * 64 + tid;
    float s = load1<F>(gamma, c) * rsqrtf(var + 1e-5f);
    sc[b * 512 + c] = s;
    bs[b * 512 + c] = load1<F>(beta, c) - mu * s;
  }
}

template <bool F, bool BEXT, bool FOUT>
__global__ void __launch_bounds__(256) gemm64(const void* __restrict__ A,
                                              const void* __restrict__ B,
                                              const float* __restrict__ sc,
                                              const float* __restrict__ bs,
                                              const void* __restrict__ bias,
                                              const void* __restrict__ resid,
                                              void* __restrict__ outp,
                                              int mrows, int donorm, int bstride,
                                              const int* __restrict__ flag) {
  if ((flag[0] != 0) != F) return;
  const int s0 = blockIdx.x * 64;
  const int o0 = blockIdx.y * 64;
  const int b  = blockIdx.z;
  __shared__ __align__(16) float At[64][36];
  __shared__ __align__(16) float Bt[64][36];
  const int tid = threadIdx.x;
  const int ty = tid >> 4, tx = tid & 15;
  const int i0 = ty * 4, j0 = tx * 4;
  const int arow = tid >> 2, akc = (tid & 3) * 8;
  const int brow = tid >> 3, bnc = (tid & 7) * 8;
  float acc[4][4] = {};

  for (int kt = 0; kt < 512; kt += 32) {
    float af[8];
    load8<F>(A, (size_t)(o0 + arow) * 512 + akc + kt, af);
    *(float4*)&At[arow][akc]     = make_float4(af[0], af[1], af[2], af[3]);
    *(float4*)&At[arow][akc + 4] = make_float4(af[4], af[5], af[6], af[7]);
    const int c = kt + brow;
    float bf[8];
    load8<(BEXT && F)>(B, (size_t)(b * bstride + c) * 1024 + s0 + bnc, bf);
    float smul = 1.f, badd = 0.f;
    if (donorm) { smul = sc[b * 512 + c]; badd = bs[b * 512 + c]; }
#pragma unroll
    for (int m = 0; m < 8; ++m) Bt[bnc + m][brow] = bf[m] * smul + badd;
    __syncthreads();
#pragma unroll
    for (int kq = 0; kq < 8; ++kq) {
      float4 a0 = *(const float4*)&At[i0 + 0][kq * 4];
      float4 a1 = *(const float4*)&At[i0 + 1][kq * 4];
      float4 a2 = *(const float4*)&At[i0 + 2][kq * 4];
      float4 a3 = *(const float4*)&At[i0 + 3][kq * 4];
      float4 c0 = *(const float4*)&Bt[j0 + 0][kq * 4];
      float4 c1 = *(const float4*)&Bt[j0 + 1][kq * 4];
      float4 c2 = *(const float4*)&Bt[j0 + 2][kq * 4];
      float4 c3 = *(const float4*)&Bt[j0 + 3][kq * 4];
#define DOT4(ii, jj, AV, CV) acc[ii][jj] += AV.x * CV.x + AV.y * CV.y + AV.z * CV.z + AV.w * CV.w;
      DOT4(0,0,a0,c0) DOT4(0,1,a0,c1) DOT4(0,2,a0,c2) DOT4(0,3,a0,c3)
      DOT4(1,0,a1,c0) DOT4(1,1,a1,c1) DOT4(1,2,a1,c2) DOT4(1,3,a1,c3)
      DOT4(2,0,a2,c0) DOT4(2,1,a2,c1) DOT4(2,2,a2,c2) DOT4(2,3,a2,c3)
      DOT4(3,0,a3,c0) DOT4(3,1,a3,c1) DOT4(3,2,a3,c2) DOT4(3,3,a3,c3)
#undef DOT4
    }
    __syncthreads();
  }
#pragma unroll
  for (int ii = 0; ii < 4; ++ii) {
    const int o = o0 + i0 + ii;
    const float bb = load1<F>(bias, o);
    float v[4];
#pragma unroll
    for (int jj = 0; jj < 4; ++jj) v[jj] = acc[ii][jj] + bb;
    if (resid) {
      float xf[4];
      load4<F>(resid, (size_t)(b * 512 + o) * 1024 + s0 + j0, xf);
#pragma unroll
      for (int jj = 0; jj < 4; ++jj) v[jj] += xf[jj];
    }
    const size_t ooff = (size_t)(b * mrows + o) * 1024 + s0 + j0;
    if constexpr (FOUT) {
      *(float4*)((float*)outp + ooff) = make_float4(v[0], v[1], v[2], v[3]);
    } else {
      uint2 pk;
      pk.x = (u32)f2bf(v[0]) | ((u32)f2bf(v[1]) << 16);
      pk.y = (u32)f2bf(v[2]) | ((u32)f2bf(v[3]) << 16);
      *(uint2*)((u16*)outp + ooff) = pk;
    }
  }
}

__global__ void __launch_bounds__(256, 2) attn_old(u16* __restrict__ qkv) {
  const int q0 = blockIdx.x * 128;
  const int bh = blockIdx.y;
  const int b = bh >> 2, h = bh & 3;
  u16* qp = qkv + (size_t)(b * 1536 + h * 128) * 1024;
  const u16* kp = qp + (size_t)512 * 1024;
  const u16* vp = qp + (size_t)1024 * 1024;
  __shared__ __align__(16) u16 Qt[128][136];
  __shared__ __align__(16) u16 Kt[32][136];
  __shared__ __align__(16) u16 Vt[128][40];
  __shared__ __align__(16) u16 Pt[128][40];
  const int tid = threadIdx.x;
  const int w = tid >> 6, lane = tid & 63;
  const int lo = lane & 31, hi = lane >> 5;

  for (int idx = tid; idx < 2048; idx += 256) {
    int d = idx >> 4, s8 = (idx & 15) * 8;
    uint4 qv = *(const uint4*)(qp + (size_t)d * 1024 + q0 + s8);
    const u16* qs = (const u16*)&qv;
#pragma unroll
    for (int m = 0; m < 8; ++m) Qt[s8 + m][d] = qs[m];
  }
  __syncthreads();
  bf16x8 qf[8];
#pragma unroll
  for (int kq = 0; kq < 8; ++kq)
    qf[kq] = *(const bf16x8*)&Qt[32 * w + lo][kq * 16 + hi * 8];

  f32x16 o0, o1, o2, o3;
  float lp[16];
#pragma unroll
  for (int r = 0; r < 16; ++r) { o0[r] = 0.f; o1[r] = 0.f; o2[r] = 0.f; o3[r] = 0.f; lp[r] = 0.f; }

  for (int kt = 0; kt < 32; ++kt) {
    const int k0 = kt * 32;
    __syncthreads();
    for (int idx = tid; idx < 512; idx += 256) {
      int d = idx >> 2, s8 = (idx & 3) * 8;
      uint4 kv = *(const uint4*)(kp + (size_t)d * 1024 + k0 + s8);
      const u16* ks = (const u16*)&kv;
#pragma unroll
      for (int m = 0; m < 8; ++m) Kt[s8 + m][d] = ks[m];
      *(uint4*)&Vt[d][s8] = *(const uint4*)(vp + (size_t)d * 1024 + k0 + s8);
    }
    __syncthreads();
    f32x16 acc;
#pragma unroll
    for (int r = 0; r < 16; ++r) acc[r] = 0.f;
#pragma unroll
    for (int kq = 0; kq < 8; ++kq) {
      bf16x8 bq = *(const bf16x8*)&Kt[lo][kq * 16 + hi * 8];
      acc = MFMA32(qf[kq], bq, acc);
    }
#pragma unroll
    for (int r = 0; r < 16; ++r) {
      float pe = __expf(acc[r] * SM_SCALE);
      lp[r] += pe;
      int row = (r & 3) + 8 * (r >> 2) + 4 * hi;
      Pt[32 * w + row][lo] = f2bf(pe);
    }
    __syncthreads();
#pragma unroll
    for (int kq2 = 0; kq2 < 2; ++kq2) {
      bf16x8 a2 = *(const bf16x8*)&Pt[32 * w + lo][kq2 * 16 + hi * 8];
      bf16x8 b0 = *(const bf16x8*)&Vt[ 0 + lo][kq2 * 16 + hi * 8];
      bf16x8 b1 = *(const bf16x8*)&Vt[32 + lo][kq2 * 16 + hi * 8];
      bf16x8 b2 = *(const bf16x8*)&Vt[64 + lo][kq2 * 16 + hi * 8];
      bf16x8 b3 = *(const bf16x8*)&Vt[96 + lo][kq2 * 16 + hi * 8];
      o0 = MFMA32(a2, b0, o0);
      o1 = MFMA32(a2, b1, o1);
      o2 = MFMA32(a2, b2, o2);
      o3 = MFMA32(a2, b3, o3);
    }
  }
#pragma unroll
  for (int r = 0; r < 16; ++r) {
    float su = lp[r];
    su += __shfl_xor(su, 1);  su += __shfl_xor(su, 2);
    su += __shfl_xor(su, 4);  su += __shfl_xor(su, 8);
    su += __shfl_xor(su, 16);
    float linv = 1.f / su;
    int row = (r & 3) + 8 * (r >> 2) + 4 * hi;
    int q = q0 + 32 * w + row;
    size_t base = (size_t)(b * 1536 + h * 128) * 1024 + q;
    qkv[base + (size_t)( 0 + lo) * 1024] = f2bf(o0[r] * linv);
    qkv[base + (size_t)(32 + lo) * 1024] = f2bf(o1[r] * linv);
    qkv[base + (size_t)(64 + lo) * 1024] = f2bf(o2[r] * linv);
    qkv[base + (size_t)(96 + lo) * 1024] = f2bf(o3[r] * linv);
  }
}

// ---------- launch ----------
extern "C" void kernel_launch(void* const* d_in, const int* in_sizes, int n_in,
                              void* d_out, int out_size, void* d_ws, size_t ws_size,
                              hipStream_t stream) {
  const void* x     = d_in[0];
  const void* gamma = d_in[1];
  const void* beta  = d_in[2];
  const void* qkvw  = d_in[3];
  const void* qkvb  = d_in[4];
  const void* projw = d_in[5];
  const void* projb = d_in[6];

  char* ws = (char*)d_ws;
  const size_t MB = 1024 * 1024;
  const size_t FAST_NEED = 64 * MB + 64;
  const size_t OLD_NEED  = 48 * MB + 256 + 2 * 16 * 512 * 4;

  if (ws_size >= FAST_NEED) {
    u16* xT   = (u16*)ws;                 // [16][1024][512] normalized; reused as aout
    u16* qkT  = (u16*)(ws + 16 * MB);     // [16][1024][1024] (Q'|K per token row)
    u16* Vbuf = (u16*)(ws + 48 * MB);     // [16][512][1024]
    u16* wbf  = (u16*)d_out;              // bf16 qkv weights+bias (1.54 MB);
                                          // dead region until proj overwrites
    float* part = (float*)((char*)d_out + 2 * MB);  // [16][8][2][2] gn partials
                                          // (dead d_out region past wbf;
                                          //  consumed before proj writes)

    // merged wconv + gn_stats (r9: detect dropped — per-block inline flag)
    prep_rt<<<641, 256, 0, stream>>>(x, qkvw, qkvb, wbf, part);
    // GroupNorm apply: 1024 blocks = 4/CU (was 256 = 1/CU, memory-bound)
    gn_apply<<<dim3(16, 16, 4), 256, 0, stream>>>(x, gamma, beta, part, xT);

    // merged qk + v GEMM (single-buffer, natural block map — r3 config)
    gemm_qkv<<<dim3(8, 12, 16), 256, 0, stream>>>(xT, wbf, qkT, Vbuf);

    attn4<<<dim3(64, 8), 256, 0, stream>>>(qkT, Vbuf, xT);  // aout overwrites xT

    // proj: D[o][s] = projW[o][:] . aout[s][:] + proj_b[o] + x
    proj_rt<<<dim3(8, 4, 16), 256, 0, stream>>>(projw, xT, projb, x, d_out);
    return;
  }

  if (ws_size < OLD_NEED) {
    signal_ws<<<(out_size + 255) / 256, 256, 0, stream>>>((u16*)d_out, out_size);
    return;
  }

  // ---- round-4 fallback ----
  const size_t QKV_BYTES = (size_t)16 * 1536 * 1024 * 2;
  u16* qkv  = (u16*)ws;
  int* flag = (int*)(ws + QKV_BYTES);
  float* sc = (float*)(ws + QKV_BYTES + 256);
  float* bs = sc + 16 * 512;

  detect_dtype<<<1, 64, 0, stream>>>(x, flag);
  gn_stats<false><<<dim3(8, 16), 256, 0, stream>>>(x, gamma, beta, sc, bs, flag);
  gn_stats<true ><<<dim3(8, 16), 256, 0, stream>>>(x, gamma, beta, sc, bs, flag);
  gemm64<false, true, false><<<dim3(16, 24, 16), 256, 0, stream>>>(
      qkvw, x, sc, bs, qkvb, nullptr, qkv, 1536, 1, 512, flag);
  gemm64<true, true, false><<<dim3(16, 24, 16), 256, 0, stream>>>(
      qkvw, x, sc, bs, qkvb, nullptr, qkv, 1536, 1, 512, flag);
  attn_old<<<dim3(8, 64), 256, 0, stream>>>(qkv);
  gemm64<false, false, false><<<dim3(16, 8, 16), 256, 0, stream>>>(
      projw, qkv, sc, bs, projb, x, d_out, 512, 0, 1536, flag);
  gemm64<true, false, true><<<dim3(16, 8, 16), 256, 0, stream>>>(
      projw, qkv, sc, bs, projb, x, d_out, 512, 0, 1536, flag);
}